// Round 4
// baseline (1450.988 us; speedup 1.0000x reference)
//
#include <hip/hip_runtime.h>
#include <math.h>

#define NNODES 100000
#define NEDGES 1600000
#define NGRAPH 256
#define NCONV  3
#define TBL    2048
#define NB1    98          // ceil(100000/1024)
#define R_MIN_ 1.0f
#define R_MAX_ 6.0f

__device__ __forceinline__ float softplus_f(float x){
  return fmaxf(x, 0.f) + __logf(1.f + __expf(-fabsf(x)));
}
__device__ __forceinline__ float sigmoid_f(float x){
  return __builtin_amdgcn_rcpf(1.f + __expf(-x));
}
__device__ __forceinline__ void fma4(float4& a, float s, const float4 w){
  a.x = fmaf(s, w.x, a.x); a.y = fmaf(s, w.y, a.y);
  a.z = fmaf(s, w.z, a.z); a.w = fmaf(s, w.w, a.w);
}

// ---------------- init ----------------
__global__ void k_init(int* deg, float* gsum, int* gcnt){
  int i = blockIdx.x*256 + threadIdx.x;
  if (i < NNODES) deg[i] = 0;
  if (i < NGRAPH){ gsum[i] = 0.f; gcnt[i] = 0; }
}

// ---------------- embedding gather ----------------
__global__ void k_embed(const int* __restrict__ numbers, const float* __restrict__ embed,
                        float* __restrict__ x){
  int i = blockIdx.x*256 + threadIdx.x;
  if (i >= NNODES*64) return;
  int n = i >> 6, c = i & 63;
  x[i] = embed[numbers[n]*64 + c];
}

// ---------------- CSR build ----------------
__global__ void k_hist(const int* __restrict__ src, int* deg){
  int e = blockIdx.x*256 + threadIdx.x;
  if (e < NEDGES) atomicAdd(&deg[src[e]], 1);
}

__global__ void k_scan1(const int* __restrict__ deg, int* __restrict__ offs, int* __restrict__ bsum){
  __shared__ int s[1024];
  int n = blockIdx.x*1024 + threadIdx.x;
  int v = (n < NNODES) ? deg[n] : 0;
  s[threadIdx.x] = v;
  __syncthreads();
  for (int d = 1; d < 1024; d <<= 1){
    int t = (threadIdx.x >= d) ? s[threadIdx.x - d] : 0;
    __syncthreads();
    s[threadIdx.x] += t;
    __syncthreads();
  }
  int incl = s[threadIdx.x];
  if (n < NNODES) offs[n] = incl - v;
  if (threadIdx.x == 1023) bsum[blockIdx.x] = incl;
}

__global__ void k_scan2(const int* __restrict__ bsum, int* __restrict__ bbase, int* __restrict__ offs){
  if (blockIdx.x == 0 && threadIdx.x == 0){
    int run = 0;
    for (int b = 0; b < NB1; b++){ int t = bsum[b]; bbase[b] = run; run += t; }
    offs[NNODES] = NEDGES;
  }
}

__global__ void k_scan3(int* __restrict__ offs, const int* __restrict__ bbase, int* __restrict__ cur){
  int n = blockIdx.x*256 + threadIdx.x;
  if (n < NNODES){
    int o = offs[n] + bbase[n >> 10];
    offs[n] = o;
    cur[n]  = o;
  }
}

__global__ void k_scatter(const int* __restrict__ src, const int* __restrict__ tgt,
                          const float* __restrict__ elen, int* cur,
                          int* __restrict__ stgt, float* __restrict__ skey){
  int e = blockIdx.x*256 + threadIdx.x;
  if (e >= NEDGES) return;
  int s = src[e];
  int pos = atomicAdd(&cur[s], 1);
  stgt[pos] = tgt[e];
  float key = (elen[e] - R_MIN_) * ((float)(TBL-1)/(R_MAX_-R_MIN_));
  key = fminf(fmaxf(key, 0.f), (float)(TBL-1) - 1e-3f);
  skey[pos] = key;
}

// ---------------- Gaussian table ----------------
__global__ void k_gauss(const float* __restrict__ Wf, const float* __restrict__ bf,
                        const float* __restrict__ Ws, const float* __restrict__ bs,
                        float* __restrict__ Gt){
  __shared__ float attr[64];
  int bi = blockIdx.x;
  int i = bi / TBL, r = bi % TBL;
  int t = threadIdx.x;
  float d = R_MIN_ + (R_MAX_-R_MIN_) * (float)r / (float)(TBL-1);
  if (t < 64){
    float cj = 1.f + 5.f * (float)t / 63.f;
    float u = (d - cj) * (64.f/5.f);
    attr[t] = __expf(-0.5f*u*u);
  }
  __syncthreads();
  int c = t >> 1;
  bool sside = (t & 1);
  const float* W = (sside ? Ws : Wf) + i*192*64 + 128*64 + c;
  float acc = (sside ? bs : bf)[i*64 + c];
  #pragma unroll 8
  for (int j = 0; j < 64; j++) acc = fmaf(attr[j], W[j*64], acc);
  Gt[(i*TBL + r)*128 + t] = acc;
}

// ---------------- Wcat pack ----------------
__global__ void k_wcat(const float* __restrict__ Wf, const float* __restrict__ Ws,
                       float* __restrict__ Wcat){
  int idx = blockIdx.x*256 + threadIdx.x;
  if (idx >= 3*64*256) return;
  int i = idx / (64*256);
  int rem = idx % (64*256);
  int k = rem / 256, c = rem % 256;
  float v;
  if (c < 128){
    int p = c >> 1; bool ss = (c & 1);
    v = (ss ? Ws : Wf)[i*192*64 + k*64 + p];
  } else {
    int p = (c-128) >> 1; bool ss = (c & 1);
    v = (ss ? Ws : Wf)[i*192*64 + (64+k)*64 + p];
  }
  Wcat[i*64*256 + k*256 + c] = v;
}

// ---------------- node transform: 32 nodes x 256 cols, weights in LDS ----------------
__global__ void k_ntrans(const float* __restrict__ x, const float* __restrict__ Wc,
                         float* __restrict__ tab){
  __shared__ float ws[64*256];      // 64 KB
  __shared__ float xs[32*64];       // 8 KB
  int n0 = blockIdx.x * 32;         // 3125 blocks exact
  int t = threadIdx.x;              // 256
  #pragma unroll
  for (int i = 0; i < 16; i++)
    ((float4*)ws)[t + i*256] = ((const float4*)Wc)[t + i*256];
  ((float4*)xs)[t]       = ((const float4*)(x + (size_t)n0*64))[t];
  ((float4*)xs)[t + 256] = ((const float4*)(x + (size_t)n0*64))[t + 256];
  __syncthreads();
  int cg = t & 63, ng = t >> 6;     // 64 col-groups x 4 cols; 4 node-groups x 8 nodes
  float4 acc[8];
  #pragma unroll
  for (int i = 0; i < 8; i++) acc[i] = make_float4(0.f,0.f,0.f,0.f);
  const float* wp = ws + 4*cg;
  const float* xp = xs + ng*8*64;
  #pragma unroll 4
  for (int k = 0; k < 64; k += 4){
    float4 w0 = *(const float4*)(wp + (k+0)*256);
    float4 w1 = *(const float4*)(wp + (k+1)*256);
    float4 w2 = *(const float4*)(wp + (k+2)*256);
    float4 w3 = *(const float4*)(wp + (k+3)*256);
    #pragma unroll
    for (int nn = 0; nn < 8; nn++){
      float4 xv = *(const float4*)(xp + nn*64 + k);
      fma4(acc[nn], xv.x, w0); fma4(acc[nn], xv.y, w1);
      fma4(acc[nn], xv.z, w2); fma4(acc[nn], xv.w, w3);
    }
  }
  #pragma unroll
  for (int nn = 0; nn < 8; nn++)
    *(float4*)(tab + (size_t)(n0 + ng*8 + nn)*256 + 4*cg) = acc[nn];
}

// ---------------- edge pass: wave per node, 4-edge pipelined ----------------
__global__ void k_edge(const float* __restrict__ tab, const int* __restrict__ offs,
                       const int* __restrict__ stgt, const float* __restrict__ skey,
                       const float* __restrict__ Gt, const float* __restrict__ lng,
                       const float* __restrict__ lnb, float* __restrict__ x){
  int wid  = (blockIdx.x*256 + threadIdx.x) >> 6;
  int lane = threadIdx.x & 63;
  int n = wid;
  float2 pq = *(const float2*)(tab + (size_t)n*256 + 2*lane);
  float pf = pq.x, ps = pq.y;
  int j0 = offs[n], j1 = offs[n+1];
  float acc = 0.f;
  for (int jb = j0; jb < j1; jb += 64){
    int cnt = min(64, j1 - jb);
    int   t_l = (jb + lane < j1) ? stgt[jb + lane] : 0;
    float k_l = (jb + lane < j1) ? skey[jb + lane] : 0.f;
    for (int u = 0; u < cnt; u += 4){
      float2 qv[4], r0v[4], r1v[4];
      float fr[4];
      float okm[4];
      #pragma unroll
      for (int i = 0; i < 4; i++){
        int ui = u + i;
        okm[i] = (ui < cnt) ? 1.f : 0.f;
        int us = (ui < cnt) ? ui : (cnt - 1);
        int   tg  = __shfl(t_l, us, 64);
        float key = __shfl(k_l, us, 64);
        int idx = (int)key;
        fr[i] = key - (float)idx;
        qv[i]  = *(const float2*)(tab + (size_t)tg*256 + 128 + 2*lane);
        const float* g0 = Gt + (size_t)idx*128 + 2*lane;
        r0v[i] = *(const float2*)(g0);
        r1v[i] = *(const float2*)(g0 + 128);
      }
      #pragma unroll
      for (int i = 0; i < 4; i++){
        float rf = fmaf(fr[i], r1v[i].x - r0v[i].x, r0v[i].x);
        float rs = fmaf(fr[i], r1v[i].y - r0v[i].y, r0v[i].y);
        float zf = pf + qv[i].x + rf;
        float zs = ps + qv[i].y + rs;
        acc = fmaf(sigmoid_f(zf) * softplus_f(zs), okm[i], acc);
      }
    }
  }
  float s1 = acc, s2 = acc*acc;
  #pragma unroll
  for (int o = 32; o > 0; o >>= 1){ s1 += __shfl_xor(s1, o, 64); s2 += __shfl_xor(s2, o, 64); }
  float mu  = s1 * (1.f/64.f);
  float var = s2 * (1.f/64.f) - mu*mu;
  float inv = rsqrtf(fmaxf(var, 0.f) + 1e-5f);
  float y = (acc - mu) * inv * lng[lane] + lnb[lane];
  x[(size_t)n*64 + lane] += y;
}

// ---------------- head layer 1: 32 nodes x 128 cols, weights in LDS ----------------
__global__ void k_h1(const float* __restrict__ x, const float* __restrict__ W1,
                     const float* __restrict__ b1, const float* __restrict__ g1,
                     const float* __restrict__ bt1, float* __restrict__ h){
  __shared__ float ws[64*128];      // 32 KB
  __shared__ float xs[32*64];       // 8 KB
  int n0 = blockIdx.x * 32;         // 3125 blocks
  int t = threadIdx.x;              // 256
  #pragma unroll
  for (int i = 0; i < 8; i++)
    ((float4*)ws)[t + i*256] = ((const float4*)W1)[t + i*256];
  ((float4*)xs)[t]       = ((const float4*)(x + (size_t)n0*64))[t];
  ((float4*)xs)[t + 256] = ((const float4*)(x + (size_t)n0*64))[t + 256];
  __syncthreads();
  int cg = t & 31, ng = t >> 5;     // 32 col-groups x 4 cols; 8 node-groups x 4 nodes
  float4 acc[4];
  #pragma unroll
  for (int i = 0; i < 4; i++) acc[i] = make_float4(0.f,0.f,0.f,0.f);
  const float* wp = ws + 4*cg;
  const float* xp = xs + ng*4*64;
  #pragma unroll 4
  for (int k = 0; k < 64; k += 4){
    float4 w0 = *(const float4*)(wp + (k+0)*128);
    float4 w1 = *(const float4*)(wp + (k+1)*128);
    float4 w2 = *(const float4*)(wp + (k+2)*128);
    float4 w3 = *(const float4*)(wp + (k+3)*128);
    #pragma unroll
    for (int nn = 0; nn < 4; nn++){
      float4 xv = *(const float4*)(xp + nn*64 + k);
      fma4(acc[nn], xv.x, w0); fma4(acc[nn], xv.y, w1);
      fma4(acc[nn], xv.z, w2); fma4(acc[nn], xv.w, w3);
    }
  }
  float4 bv  = *(const float4*)(b1  + 4*cg);
  float4 gv  = *(const float4*)(g1  + 4*cg);
  float4 btv = *(const float4*)(bt1 + 4*cg);
  #pragma unroll
  for (int nn = 0; nn < 4; nn++){
    float4 v = acc[nn];
    v.x += bv.x; v.y += bv.y; v.z += bv.z; v.w += bv.w;
    float s1 = v.x + v.y + v.z + v.w;
    float s2 = v.x*v.x + v.y*v.y + v.z*v.z + v.w*v.w;
    #pragma unroll
    for (int o = 16; o > 0; o >>= 1){ s1 += __shfl_xor(s1, o, 64); s2 += __shfl_xor(s2, o, 64); }
    float mu  = s1 * (1.f/128.f);
    float var = s2 * (1.f/128.f) - mu*mu;
    float inv = rsqrtf(fmaxf(var, 0.f) + 1e-5f);
    float4 o4;
    o4.x = softplus_f((v.x - mu)*inv*gv.x + btv.x);
    o4.y = softplus_f((v.y - mu)*inv*gv.y + btv.y);
    o4.z = softplus_f((v.z - mu)*inv*gv.z + btv.z);
    o4.w = softplus_f((v.w - mu)*inv*gv.w + btv.w);
    *(float4*)(h + (size_t)(n0 + ng*4 + nn)*128 + 4*cg) = o4;
  }
}

// ---------------- head layer 2 + out proj + segment sum: weights in LDS ----------------
__global__ void k_h2(const float* __restrict__ h, const float* __restrict__ W2,
                     const float* __restrict__ b2, const float* __restrict__ g2,
                     const float* __restrict__ bt2, const float* __restrict__ Wout,
                     const int* __restrict__ batch, float* gsum, int* gcnt){
  __shared__ float ws[128*128];     // 64 KB
  __shared__ float hs[32*128];      // 16 KB  (total 80 KB -> 2 blocks/CU)
  int n0 = blockIdx.x * 32;         // 3125 blocks
  int t = threadIdx.x;              // 256
  #pragma unroll
  for (int i = 0; i < 16; i++)
    ((float4*)ws)[t + i*256] = ((const float4*)W2)[t + i*256];
  {
    const float4* hp = (const float4*)(h + (size_t)n0*128);
    ((float4*)hs)[t]       = hp[t];
    ((float4*)hs)[t + 256] = hp[t + 256];
    ((float4*)hs)[t + 512] = hp[t + 512];
    ((float4*)hs)[t + 768] = hp[t + 768];
  }
  __syncthreads();
  int cg = t & 31, ng = t >> 5;     // 32 col-groups x 4 cols; 8 node-groups x 4 nodes
  float4 acc[4];
  #pragma unroll
  for (int i = 0; i < 4; i++) acc[i] = make_float4(0.f,0.f,0.f,0.f);
  const float* wp = ws + 4*cg;
  const float* hp = hs + ng*4*128;
  #pragma unroll 4
  for (int k = 0; k < 128; k += 4){
    float4 w0 = *(const float4*)(wp + (k+0)*128);
    float4 w1 = *(const float4*)(wp + (k+1)*128);
    float4 w2 = *(const float4*)(wp + (k+2)*128);
    float4 w3 = *(const float4*)(wp + (k+3)*128);
    #pragma unroll
    for (int nn = 0; nn < 4; nn++){
      float4 hv = *(const float4*)(hp + nn*128 + k);
      fma4(acc[nn], hv.x, w0); fma4(acc[nn], hv.y, w1);
      fma4(acc[nn], hv.z, w2); fma4(acc[nn], hv.w, w3);
    }
  }
  float4 bv  = *(const float4*)(b2  + 4*cg);
  float4 gv  = *(const float4*)(g2  + 4*cg);
  float4 btv = *(const float4*)(bt2 + 4*cg);
  float4 wo  = *(const float4*)(Wout + 4*cg);
  #pragma unroll
  for (int nn = 0; nn < 4; nn++){
    float4 v = acc[nn];
    v.x += bv.x; v.y += bv.y; v.z += bv.z; v.w += bv.w;
    float s1 = v.x + v.y + v.z + v.w;
    float s2 = v.x*v.x + v.y*v.y + v.z*v.z + v.w*v.w;
    #pragma unroll
    for (int o = 16; o > 0; o >>= 1){ s1 += __shfl_xor(s1, o, 64); s2 += __shfl_xor(s2, o, 64); }
    float mu  = s1 * (1.f/128.f);
    float var = s2 * (1.f/128.f) - mu*mu;
    float inv = rsqrtf(fmaxf(var, 0.f) + 1e-5f);
    float ev = softplus_f((v.x - mu)*inv*gv.x + btv.x) * wo.x
             + softplus_f((v.y - mu)*inv*gv.y + btv.y) * wo.y
             + softplus_f((v.z - mu)*inv*gv.z + btv.z) * wo.z
             + softplus_f((v.w - mu)*inv*gv.w + btv.w) * wo.w;
    #pragma unroll
    for (int o = 16; o > 0; o >>= 1) ev += __shfl_xor(ev, o, 64);
    if (cg == 0){
      int node = n0 + ng*4 + nn;
      int gr = batch[node];
      atomicAdd(&gsum[gr], ev);
      atomicAdd(&gcnt[gr], 1);
    }
  }
}

// ---------------- final ----------------
__global__ void k_final(const float* __restrict__ gsum, const int* __restrict__ gcnt,
                        const float* __restrict__ bout, float* __restrict__ out){
  int g = threadIdx.x;
  if (g < NGRAPH)
    out[g] = gsum[g] / fmaxf((float)gcnt[g], 1.f) + bout[0];
}

extern "C" void kernel_launch(void* const* d_in, const int* in_sizes, int n_in,
                              void* d_out, int out_size, void* d_ws, size_t ws_size,
                              hipStream_t stream){
  const int*   numbers = (const int*)d_in[0];
  const int*   eidx    = (const int*)d_in[1];
  const float* elen    = (const float*)d_in[2];
  const int*   batch   = (const int*)d_in[3];
  const float* embed   = (const float*)d_in[4];
  const float* Wf      = (const float*)d_in[5];
  const float* bf      = (const float*)d_in[6];
  const float* Ws      = (const float*)d_in[7];
  const float* bs      = (const float*)d_in[8];
  const float* lng     = (const float*)d_in[9];
  const float* lnb     = (const float*)d_in[10];
  const float* W1      = (const float*)d_in[11];
  const float* b1      = (const float*)d_in[12];
  const float* g1      = (const float*)d_in[13];
  const float* bt1     = (const float*)d_in[14];
  const float* W2      = (const float*)d_in[15];
  const float* b2      = (const float*)d_in[16];
  const float* g2      = (const float*)d_in[17];
  const float* bt2     = (const float*)d_in[18];
  const float* Wout    = (const float*)d_in[19];
  const float* bout    = (const float*)d_in[20];
  const int* src = eidx;
  const int* tgt = eidx + NEDGES;

  float* x    = (float*)d_ws;                         // N*64
  float* tab  = x    + (size_t)NNODES*64;             // N*256
  float* Gt   = tab  + (size_t)NNODES*256;            // 3*TBL*128
  float* Wcat = Gt   + (size_t)3*TBL*128;             // 3*64*256
  float* skey = Wcat + (size_t)3*64*256;              // E
  int*   stgt = (int*)(skey + NEDGES);                // E
  int*   offs = stgt + NEDGES;                        // N+1
  int*   cur  = offs + NNODES + 1;                    // N
  int*   deg  = cur  + NNODES;                        // N
  int*   bsum = deg  + NNODES;                        // 128
  int*   bbase= bsum + 128;                           // 128
  float* gsum = (float*)(bbase + 128);                // 256
  int*   gcnt = (int*)(gsum + NGRAPH);                // 256
  float* h    = tab;                                  // reuse
  float* out  = (float*)d_out;

  k_init  <<<(NNODES+255)/256, 256, 0, stream>>>(deg, gsum, gcnt);
  k_embed <<<(NNODES*64+255)/256, 256, 0, stream>>>(numbers, embed, x);

  k_hist   <<<(NEDGES+255)/256, 256, 0, stream>>>(src, deg);
  k_scan1  <<<NB1, 1024, 0, stream>>>(deg, offs, bsum);
  k_scan2  <<<1, 64, 0, stream>>>(bsum, bbase, offs);
  k_scan3  <<<(NNODES+255)/256, 256, 0, stream>>>(offs, bbase, cur);
  k_scatter<<<(NEDGES+255)/256, 256, 0, stream>>>(src, tgt, elen, cur, stgt, skey);

  k_gauss <<<3*TBL, 128, 0, stream>>>(Wf, bf, Ws, bs, Gt);
  k_wcat  <<<(3*64*256+255)/256, 256, 0, stream>>>(Wf, Ws, Wcat);

  for (int i = 0; i < NCONV; i++){
    k_ntrans<<<NNODES/32, 256, 0, stream>>>(x, Wcat + (size_t)i*64*256, tab);
    k_edge  <<<NNODES/4, 256, 0, stream>>>(tab, offs, stgt, skey,
                                           Gt + (size_t)i*TBL*128,
                                           lng + i*64, lnb + i*64, x);
  }

  k_h1<<<NNODES/32, 256, 0, stream>>>(x, W1, b1, g1, bt1, h);
  k_h2<<<NNODES/32, 256, 0, stream>>>(h, W2, b2, g2, bt2, Wout, batch, gsum, gcnt);
  k_final<<<1, 256, 0, stream>>>(gsum, gcnt, bout, out);
}

// Round 5
// 1262.858 us; speedup vs baseline: 1.1490x; 1.1490x over previous
//
#include <hip/hip_runtime.h>
#include <math.h>

#define NNODES 100000
#define NEDGES 1600000
#define NGRAPH 256
#define NCONV  3
#define TBL    2048
#define NB1    98          // ceil(100000/1024)
#define R_MIN_ 1.0f
#define R_MAX_ 6.0f

__device__ __forceinline__ float softplus_f(float x){
  return fmaxf(x, 0.f) + __logf(1.f + __expf(-fabsf(x)));
}
__device__ __forceinline__ float sigmoid_f(float x){
  return __builtin_amdgcn_rcpf(1.f + __expf(-x));
}
__device__ __forceinline__ void fma4(float4& a, float s, const float4 w){
  a.x = fmaf(s, w.x, a.x); a.y = fmaf(s, w.y, a.y);
  a.z = fmaf(s, w.z, a.z); a.w = fmaf(s, w.w, a.w);
}

// ---------------- init ----------------
__global__ void k_init(int* deg, float* gsum, int* gcnt){
  int i = blockIdx.x*256 + threadIdx.x;
  if (i < NNODES) deg[i] = 0;
  if (i < NGRAPH){ gsum[i] = 0.f; gcnt[i] = 0; }
}

// ---------------- embedding gather ----------------
__global__ void k_embed(const int* __restrict__ numbers, const float* __restrict__ embed,
                        float* __restrict__ x){
  int i = blockIdx.x*256 + threadIdx.x;
  if (i >= NNODES*64) return;
  int n = i >> 6, c = i & 63;
  x[i] = embed[numbers[n]*64 + c];
}

// ---------------- CSR build ----------------
__global__ void k_hist(const int* __restrict__ src, int* deg){
  int e = blockIdx.x*256 + threadIdx.x;
  if (e < NEDGES) atomicAdd(&deg[src[e]], 1);
}

__global__ void k_scan1(const int* __restrict__ deg, int* __restrict__ offs, int* __restrict__ bsum){
  __shared__ int s[1024];
  int n = blockIdx.x*1024 + threadIdx.x;
  int v = (n < NNODES) ? deg[n] : 0;
  s[threadIdx.x] = v;
  __syncthreads();
  for (int d = 1; d < 1024; d <<= 1){
    int t = (threadIdx.x >= d) ? s[threadIdx.x - d] : 0;
    __syncthreads();
    s[threadIdx.x] += t;
    __syncthreads();
  }
  int incl = s[threadIdx.x];
  if (n < NNODES) offs[n] = incl - v;
  if (threadIdx.x == 1023) bsum[blockIdx.x] = incl;
}

__global__ void k_scan2(const int* __restrict__ bsum, int* __restrict__ bbase, int* __restrict__ offs){
  if (blockIdx.x == 0 && threadIdx.x == 0){
    int run = 0;
    for (int b = 0; b < NB1; b++){ int t = bsum[b]; bbase[b] = run; run += t; }
    offs[NNODES] = NEDGES;
  }
}

__global__ void k_scan3(int* __restrict__ offs, const int* __restrict__ bbase, int* __restrict__ cur){
  int n = blockIdx.x*256 + threadIdx.x;
  if (n < NNODES){
    int o = offs[n] + bbase[n >> 10];
    offs[n] = o;
    cur[n]  = o;
  }
}

__global__ void k_scatter(const int* __restrict__ src, const int* __restrict__ tgt,
                          const float* __restrict__ elen, int* cur,
                          int* __restrict__ stgt, float* __restrict__ skey){
  int e = blockIdx.x*256 + threadIdx.x;
  if (e >= NEDGES) return;
  int s = src[e];
  int pos = atomicAdd(&cur[s], 1);
  stgt[pos] = tgt[e];
  float key = (elen[e] - R_MIN_) * ((float)(TBL-1)/(R_MAX_-R_MIN_));
  key = fminf(fmaxf(key, 0.f), (float)(TBL-1) - 1e-3f);
  skey[pos] = key;
}

// ---------------- Gaussian table ----------------
__global__ void k_gauss(const float* __restrict__ Wf, const float* __restrict__ bf,
                        const float* __restrict__ Ws, const float* __restrict__ bs,
                        float* __restrict__ Gt){
  __shared__ float attr[64];
  int bi = blockIdx.x;
  int i = bi / TBL, r = bi % TBL;
  int t = threadIdx.x;
  float d = R_MIN_ + (R_MAX_-R_MIN_) * (float)r / (float)(TBL-1);
  if (t < 64){
    float cj = 1.f + 5.f * (float)t / 63.f;
    float u = (d - cj) * (64.f/5.f);
    attr[t] = __expf(-0.5f*u*u);
  }
  __syncthreads();
  int c = t >> 1;
  bool sside = (t & 1);
  const float* W = (sside ? Ws : Wf) + i*192*64 + 128*64 + c;
  float acc = (sside ? bs : bf)[i*64 + c];
  #pragma unroll 8
  for (int j = 0; j < 64; j++) acc = fmaf(attr[j], W[j*64], acc);
  Gt[(i*TBL + r)*128 + t] = acc;
}

// ---------------- Wcat pack ----------------
__global__ void k_wcat(const float* __restrict__ Wf, const float* __restrict__ Ws,
                       float* __restrict__ Wcat){
  int idx = blockIdx.x*256 + threadIdx.x;
  if (idx >= 3*64*256) return;
  int i = idx / (64*256);
  int rem = idx % (64*256);
  int k = rem / 256, c = rem % 256;
  float v;
  if (c < 128){
    int p = c >> 1; bool ss = (c & 1);
    v = (ss ? Ws : Wf)[i*192*64 + k*64 + p];
  } else {
    int p = (c-128) >> 1; bool ss = (c & 1);
    v = (ss ? Ws : Wf)[i*192*64 + (64+k)*64 + p];
  }
  Wcat[i*64*256 + k*256 + c] = v;
}

// ---------------- node transform: 32 nodes x 256 cols per block (R3 style) ----------------
__global__ void k_ntrans(const float* __restrict__ x, const float* __restrict__ Wc,
                         float* __restrict__ tab){
  __shared__ float xs[32*64];       // 8 KB
  int n0 = blockIdx.x * 32;         // 3125 blocks exact
  int t = threadIdx.x;              // 256
  ((float4*)xs)[t]       = ((const float4*)(x + (size_t)n0*64))[t];
  ((float4*)xs)[t + 256] = ((const float4*)(x + (size_t)n0*64))[t + 256];
  __syncthreads();
  int cg = t & 63, ng = t >> 6;     // 64 col-groups x 4 cols; 4 node-groups x 8 nodes
  float4 acc[8];
  #pragma unroll
  for (int i = 0; i < 8; i++) acc[i] = make_float4(0.f,0.f,0.f,0.f);
  const float* wp = Wc + 4*cg;
  const float* xp = xs + ng*8*64;
  #pragma unroll 2
  for (int k = 0; k < 64; k += 4){
    float4 w0 = *(const float4*)(wp + (k+0)*256);
    float4 w1 = *(const float4*)(wp + (k+1)*256);
    float4 w2 = *(const float4*)(wp + (k+2)*256);
    float4 w3 = *(const float4*)(wp + (k+3)*256);
    #pragma unroll
    for (int nn = 0; nn < 8; nn++){
      float4 xv = *(const float4*)(xp + nn*64 + k);
      fma4(acc[nn], xv.x, w0); fma4(acc[nn], xv.y, w1);
      fma4(acc[nn], xv.z, w2); fma4(acc[nn], xv.w, w3);
    }
  }
  #pragma unroll
  for (int nn = 0; nn < 8; nn++)
    *(float4*)(tab + (size_t)(n0 + ng*8 + nn)*256 + 4*cg) = acc[nn];
}

// ---------------- edge pass: wave per node, 4-edge pipelined ----------------
__global__ void k_edge(const float* __restrict__ tab, const int* __restrict__ offs,
                       const int* __restrict__ stgt, const float* __restrict__ skey,
                       const float* __restrict__ Gt, const float* __restrict__ lng,
                       const float* __restrict__ lnb, float* __restrict__ x){
  int wid  = (blockIdx.x*256 + threadIdx.x) >> 6;
  int lane = threadIdx.x & 63;
  int n = wid;
  float2 pq = *(const float2*)(tab + (size_t)n*256 + 2*lane);
  float pf = pq.x, ps = pq.y;
  int j0 = offs[n], j1 = offs[n+1];
  float acc = 0.f;
  for (int jb = j0; jb < j1; jb += 64){
    int cnt = min(64, j1 - jb);
    int   t_l = (jb + lane < j1) ? stgt[jb + lane] : 0;
    float k_l = (jb + lane < j1) ? skey[jb + lane] : 0.f;
    for (int u = 0; u < cnt; u += 4){
      float2 qv[4], r0v[4], r1v[4];
      float fr[4];
      float okm[4];
      #pragma unroll
      for (int i = 0; i < 4; i++){
        int ui = u + i;
        okm[i] = (ui < cnt) ? 1.f : 0.f;
        int us = (ui < cnt) ? ui : (cnt - 1);
        int   tg  = __shfl(t_l, us, 64);
        float key = __shfl(k_l, us, 64);
        int idx = (int)key;
        fr[i] = key - (float)idx;
        qv[i]  = *(const float2*)(tab + (size_t)tg*256 + 128 + 2*lane);
        const float* g0 = Gt + (size_t)idx*128 + 2*lane;
        r0v[i] = *(const float2*)(g0);
        r1v[i] = *(const float2*)(g0 + 128);
      }
      #pragma unroll
      for (int i = 0; i < 4; i++){
        float rf = fmaf(fr[i], r1v[i].x - r0v[i].x, r0v[i].x);
        float rs = fmaf(fr[i], r1v[i].y - r0v[i].y, r0v[i].y);
        float zf = pf + qv[i].x + rf;
        float zs = ps + qv[i].y + rs;
        acc = fmaf(sigmoid_f(zf) * softplus_f(zs), okm[i], acc);
      }
    }
  }
  float s1 = acc, s2 = acc*acc;
  #pragma unroll
  for (int o = 32; o > 0; o >>= 1){ s1 += __shfl_xor(s1, o, 64); s2 += __shfl_xor(s2, o, 64); }
  float mu  = s1 * (1.f/64.f);
  float var = s2 * (1.f/64.f) - mu*mu;
  float inv = rsqrtf(fmaxf(var, 0.f) + 1e-5f);
  float y = (acc - mu) * inv * lng[lane] + lnb[lane];
  x[(size_t)n*64 + lane] += y;
}

// ---------------- fused head: x -> L1+LN+softplus (LDS) -> L2+LN+softplus -> proj -> seg-sum ----------------
__global__ void k_head(const float* __restrict__ x,
                       const float* __restrict__ W1, const float* __restrict__ b1,
                       const float* __restrict__ g1, const float* __restrict__ bt1,
                       const float* __restrict__ W2, const float* __restrict__ b2,
                       const float* __restrict__ g2, const float* __restrict__ bt2,
                       const float* __restrict__ Wout, const int* __restrict__ batch,
                       float* gsum, int* gcnt){
  __shared__ float xs[32*64];       // 8 KB
  __shared__ float hs[32*128];      // 16 KB (24 KB total -> ~6 blocks/CU)
  int n0 = blockIdx.x * 32;         // 3125 blocks
  int t = threadIdx.x;              // 256
  ((float4*)xs)[t]       = ((const float4*)(x + (size_t)n0*64))[t];
  ((float4*)xs)[t + 256] = ((const float4*)(x + (size_t)n0*64))[t + 256];
  __syncthreads();
  int cg = t & 31, ng = t >> 5;     // 32 col-groups x 4 cols; 8 node-groups x 4 nodes

  // ---- layer 1: 64 -> 128, LN, softplus, into hs ----
  {
    float4 acc[4];
    #pragma unroll
    for (int i = 0; i < 4; i++) acc[i] = make_float4(0.f,0.f,0.f,0.f);
    const float* wp = W1 + 4*cg;
    const float* xp = xs + ng*4*64;
    #pragma unroll 2
    for (int k = 0; k < 64; k += 4){
      float4 w0 = *(const float4*)(wp + (k+0)*128);
      float4 w1 = *(const float4*)(wp + (k+1)*128);
      float4 w2 = *(const float4*)(wp + (k+2)*128);
      float4 w3 = *(const float4*)(wp + (k+3)*128);
      #pragma unroll
      for (int nn = 0; nn < 4; nn++){
        float4 xv = *(const float4*)(xp + nn*64 + k);
        fma4(acc[nn], xv.x, w0); fma4(acc[nn], xv.y, w1);
        fma4(acc[nn], xv.z, w2); fma4(acc[nn], xv.w, w3);
      }
    }
    float4 bv  = *(const float4*)(b1  + 4*cg);
    float4 gv  = *(const float4*)(g1  + 4*cg);
    float4 btv = *(const float4*)(bt1 + 4*cg);
    #pragma unroll
    for (int nn = 0; nn < 4; nn++){
      float4 v = acc[nn];
      v.x += bv.x; v.y += bv.y; v.z += bv.z; v.w += bv.w;
      float s1 = v.x + v.y + v.z + v.w;
      float s2 = v.x*v.x + v.y*v.y + v.z*v.z + v.w*v.w;
      #pragma unroll
      for (int o = 16; o > 0; o >>= 1){ s1 += __shfl_xor(s1, o, 64); s2 += __shfl_xor(s2, o, 64); }
      float mu  = s1 * (1.f/128.f);
      float var = s2 * (1.f/128.f) - mu*mu;
      float inv = rsqrtf(fmaxf(var, 0.f) + 1e-5f);
      float4 o4;
      o4.x = softplus_f((v.x - mu)*inv*gv.x + btv.x);
      o4.y = softplus_f((v.y - mu)*inv*gv.y + btv.y);
      o4.z = softplus_f((v.z - mu)*inv*gv.z + btv.z);
      o4.w = softplus_f((v.w - mu)*inv*gv.w + btv.w);
      *(float4*)(hs + (ng*4 + nn)*128 + 4*cg) = o4;
    }
  }
  __syncthreads();

  // ---- layer 2: 128 -> 128, LN, softplus, proj, segment sum ----
  {
    float4 acc[4];
    #pragma unroll
    for (int i = 0; i < 4; i++) acc[i] = make_float4(0.f,0.f,0.f,0.f);
    const float* wp = W2 + 4*cg;
    const float* hp = hs + ng*4*128;
    #pragma unroll 2
    for (int k = 0; k < 128; k += 4){
      float4 w0 = *(const float4*)(wp + (k+0)*128);
      float4 w1 = *(const float4*)(wp + (k+1)*128);
      float4 w2 = *(const float4*)(wp + (k+2)*128);
      float4 w3 = *(const float4*)(wp + (k+3)*128);
      #pragma unroll
      for (int nn = 0; nn < 4; nn++){
        float4 hv = *(const float4*)(hp + nn*128 + k);
        fma4(acc[nn], hv.x, w0); fma4(acc[nn], hv.y, w1);
        fma4(acc[nn], hv.z, w2); fma4(acc[nn], hv.w, w3);
      }
    }
    float4 bv  = *(const float4*)(b2  + 4*cg);
    float4 gv  = *(const float4*)(g2  + 4*cg);
    float4 btv = *(const float4*)(bt2 + 4*cg);
    float4 wo  = *(const float4*)(Wout + 4*cg);
    #pragma unroll
    for (int nn = 0; nn < 4; nn++){
      float4 v = acc[nn];
      v.x += bv.x; v.y += bv.y; v.z += bv.z; v.w += bv.w;
      float s1 = v.x + v.y + v.z + v.w;
      float s2 = v.x*v.x + v.y*v.y + v.z*v.z + v.w*v.w;
      #pragma unroll
      for (int o = 16; o > 0; o >>= 1){ s1 += __shfl_xor(s1, o, 64); s2 += __shfl_xor(s2, o, 64); }
      float mu  = s1 * (1.f/128.f);
      float var = s2 * (1.f/128.f) - mu*mu;
      float inv = rsqrtf(fmaxf(var, 0.f) + 1e-5f);
      float ev = softplus_f((v.x - mu)*inv*gv.x + btv.x) * wo.x
               + softplus_f((v.y - mu)*inv*gv.y + btv.y) * wo.y
               + softplus_f((v.z - mu)*inv*gv.z + btv.z) * wo.z
               + softplus_f((v.w - mu)*inv*gv.w + btv.w) * wo.w;
      #pragma unroll
      for (int o = 16; o > 0; o >>= 1) ev += __shfl_xor(ev, o, 64);
      if (cg == 0){
        int node = n0 + ng*4 + nn;
        int gr = batch[node];
        atomicAdd(&gsum[gr], ev);
        atomicAdd(&gcnt[gr], 1);
      }
    }
  }
}

// ---------------- final ----------------
__global__ void k_final(const float* __restrict__ gsum, const int* __restrict__ gcnt,
                        const float* __restrict__ bout, float* __restrict__ out){
  int g = threadIdx.x;
  if (g < NGRAPH)
    out[g] = gsum[g] / fmaxf((float)gcnt[g], 1.f) + bout[0];
}

extern "C" void kernel_launch(void* const* d_in, const int* in_sizes, int n_in,
                              void* d_out, int out_size, void* d_ws, size_t ws_size,
                              hipStream_t stream){
  const int*   numbers = (const int*)d_in[0];
  const int*   eidx    = (const int*)d_in[1];
  const float* elen    = (const float*)d_in[2];
  const int*   batch   = (const int*)d_in[3];
  const float* embed   = (const float*)d_in[4];
  const float* Wf      = (const float*)d_in[5];
  const float* bf      = (const float*)d_in[6];
  const float* Ws      = (const float*)d_in[7];
  const float* bs      = (const float*)d_in[8];
  const float* lng     = (const float*)d_in[9];
  const float* lnb     = (const float*)d_in[10];
  const float* W1      = (const float*)d_in[11];
  const float* b1      = (const float*)d_in[12];
  const float* g1      = (const float*)d_in[13];
  const float* bt1     = (const float*)d_in[14];
  const float* W2      = (const float*)d_in[15];
  const float* b2      = (const float*)d_in[16];
  const float* g2      = (const float*)d_in[17];
  const float* bt2     = (const float*)d_in[18];
  const float* Wout    = (const float*)d_in[19];
  const float* bout    = (const float*)d_in[20];
  const int* src = eidx;
  const int* tgt = eidx + NEDGES;

  float* x    = (float*)d_ws;                         // N*64
  float* tab  = x    + (size_t)NNODES*64;             // N*256
  float* Gt   = tab  + (size_t)NNODES*256;            // 3*TBL*128
  float* Wcat = Gt   + (size_t)3*TBL*128;             // 3*64*256
  float* skey = Wcat + (size_t)3*64*256;              // E
  int*   stgt = (int*)(skey + NEDGES);                // E
  int*   offs = stgt + NEDGES;                        // N+1
  int*   cur  = offs + NNODES + 1;                    // N
  int*   deg  = cur  + NNODES;                        // N
  int*   bsum = deg  + NNODES;                        // 128
  int*   bbase= bsum + 128;                           // 128
  float* gsum = (float*)(bbase + 128);                // 256
  int*   gcnt = (int*)(gsum + NGRAPH);                // 256
  float* out  = (float*)d_out;

  k_init  <<<(NNODES+255)/256, 256, 0, stream>>>(deg, gsum, gcnt);
  k_embed <<<(NNODES*64+255)/256, 256, 0, stream>>>(numbers, embed, x);

  k_hist   <<<(NEDGES+255)/256, 256, 0, stream>>>(src, deg);
  k_scan1  <<<NB1, 1024, 0, stream>>>(deg, offs, bsum);
  k_scan2  <<<1, 64, 0, stream>>>(bsum, bbase, offs);
  k_scan3  <<<(NNODES+255)/256, 256, 0, stream>>>(offs, bbase, cur);
  k_scatter<<<(NEDGES+255)/256, 256, 0, stream>>>(src, tgt, elen, cur, stgt, skey);

  k_gauss <<<3*TBL, 128, 0, stream>>>(Wf, bf, Ws, bs, Gt);
  k_wcat  <<<(3*64*256+255)/256, 256, 0, stream>>>(Wf, Ws, Wcat);

  for (int i = 0; i < NCONV; i++){
    k_ntrans<<<NNODES/32, 256, 0, stream>>>(x, Wcat + (size_t)i*64*256, tab);
    k_edge  <<<NNODES/4, 256, 0, stream>>>(tab, offs, stgt, skey,
                                           Gt + (size_t)i*TBL*128,
                                           lng + i*64, lnb + i*64, x);
  }

  k_head<<<NNODES/32, 256, 0, stream>>>(x, W1, b1, g1, bt1,
                                        W2, b2, g2, bt2, Wout, batch, gsum, gcnt);
  k_final<<<1, 256, 0, stream>>>(gsum, gcnt, bout, out);
}

// Round 6
// 1258.641 us; speedup vs baseline: 1.1528x; 1.0034x over previous
//
#include <hip/hip_runtime.h>
#include <math.h>

#define NNODES 100000
#define NEDGES 1600000
#define NGRAPH 256
#define NCONV  3
#define TBL    2048
#define NB1    98          // ceil(100000/1024)
#define R_MIN_ 1.0f
#define R_MAX_ 6.0f

__device__ __forceinline__ float softplus_f(float x){
  return fmaxf(x, 0.f) + __logf(1.f + __expf(-fabsf(x)));
}
__device__ __forceinline__ float sigmoid_f(float x){
  return __builtin_amdgcn_rcpf(1.f + __expf(-x));
}
__device__ __forceinline__ void fma4(float4& a, float s, const float4 w){
  a.x = fmaf(s, w.x, a.x); a.y = fmaf(s, w.y, a.y);
  a.z = fmaf(s, w.z, a.z); a.w = fmaf(s, w.w, a.w);
}

// ---------------- init ----------------
__global__ void k_init(int* deg, float* gsum, int* gcnt){
  int i = blockIdx.x*256 + threadIdx.x;
  if (i < NNODES) deg[i] = 0;
  if (i < NGRAPH){ gsum[i] = 0.f; gcnt[i] = 0; }
}

// ---------------- embedding gather ----------------
__global__ void k_embed(const int* __restrict__ numbers, const float* __restrict__ embed,
                        float* __restrict__ x){
  int i = blockIdx.x*256 + threadIdx.x;
  if (i >= NNODES*64) return;
  int n = i >> 6, c = i & 63;
  x[i] = embed[numbers[n]*64 + c];
}

// ---------------- CSR build ----------------
__global__ void k_hist(const int* __restrict__ src, int* deg){
  int e = blockIdx.x*256 + threadIdx.x;
  if (e < NEDGES) atomicAdd(&deg[src[e]], 1);
}

__global__ void k_scan1(const int* __restrict__ deg, int* __restrict__ offs, int* __restrict__ bsum){
  __shared__ int s[1024];
  int n = blockIdx.x*1024 + threadIdx.x;
  int v = (n < NNODES) ? deg[n] : 0;
  s[threadIdx.x] = v;
  __syncthreads();
  for (int d = 1; d < 1024; d <<= 1){
    int t = (threadIdx.x >= d) ? s[threadIdx.x - d] : 0;
    __syncthreads();
    s[threadIdx.x] += t;
    __syncthreads();
  }
  int incl = s[threadIdx.x];
  if (n < NNODES) offs[n] = incl - v;
  if (threadIdx.x == 1023) bsum[blockIdx.x] = incl;
}

__global__ void k_scan2(const int* __restrict__ bsum, int* __restrict__ bbase, int* __restrict__ offs){
  if (blockIdx.x == 0 && threadIdx.x == 0){
    int run = 0;
    for (int b = 0; b < NB1; b++){ int t = bsum[b]; bbase[b] = run; run += t; }
    offs[NNODES] = NEDGES;
  }
}

__global__ void k_scan3(int* __restrict__ offs, const int* __restrict__ bbase, int* __restrict__ cur){
  int n = blockIdx.x*256 + threadIdx.x;
  if (n < NNODES){
    int o = offs[n] + bbase[n >> 10];
    offs[n] = o;
    cur[n]  = o;
  }
}

__global__ void k_scatter(const int* __restrict__ src, const int* __restrict__ tgt,
                          const float* __restrict__ elen, int* cur,
                          int* __restrict__ stgt, float* __restrict__ skey){
  int e = blockIdx.x*256 + threadIdx.x;
  if (e >= NEDGES) return;
  int s = src[e];
  int pos = atomicAdd(&cur[s], 1);
  stgt[pos] = tgt[e];
  float key = (elen[e] - R_MIN_) * ((float)(TBL-1)/(R_MAX_-R_MIN_));
  key = fminf(fmaxf(key, 0.f), (float)(TBL-1) - 1e-3f);
  skey[pos] = key;
}

// ---------------- Gaussian table ----------------
__global__ void k_gauss(const float* __restrict__ Wf, const float* __restrict__ bf,
                        const float* __restrict__ Ws, const float* __restrict__ bs,
                        float* __restrict__ Gt){
  __shared__ float attr[64];
  int bi = blockIdx.x;
  int i = bi / TBL, r = bi % TBL;
  int t = threadIdx.x;
  float d = R_MIN_ + (R_MAX_-R_MIN_) * (float)r / (float)(TBL-1);
  if (t < 64){
    float cj = 1.f + 5.f * (float)t / 63.f;
    float u = (d - cj) * (64.f/5.f);
    attr[t] = __expf(-0.5f*u*u);
  }
  __syncthreads();
  int c = t >> 1;
  bool sside = (t & 1);
  const float* W = (sside ? Ws : Wf) + i*192*64 + 128*64 + c;
  float acc = (sside ? bs : bf)[i*64 + c];
  #pragma unroll 8
  for (int j = 0; j < 64; j++) acc = fmaf(attr[j], W[j*64], acc);
  Gt[(i*TBL + r)*128 + t] = acc;
}

// ---------------- pack Gt rows r, r+1 into interleaved float4 table ----------------
__global__ void k_gpack(const float* __restrict__ Gt, float* __restrict__ Gt2){
  int bi = blockIdx.x;                 // 3*TBL
  int i = bi / TBL, r = bi % TBL;
  int l = threadIdx.x;                 // 0..63
  int r1 = (r + 1 < TBL) ? r + 1 : r;
  const float* g0 = Gt + ((size_t)i*TBL + r )*128;
  const float* g1 = Gt + ((size_t)i*TBL + r1)*128;
  float4 v;
  v.x = g0[2*l]; v.y = g0[2*l+1];
  v.z = g1[2*l]; v.w = g1[2*l+1];
  ((float4*)(Gt2 + ((size_t)i*TBL + r)*256))[l] = v;
}

// ---------------- Wcat pack ----------------
__global__ void k_wcat(const float* __restrict__ Wf, const float* __restrict__ Ws,
                       float* __restrict__ Wcat){
  int idx = blockIdx.x*256 + threadIdx.x;
  if (idx >= 3*64*256) return;
  int i = idx / (64*256);
  int rem = idx % (64*256);
  int k = rem / 256, c = rem % 256;
  float v;
  if (c < 128){
    int p = c >> 1; bool ss = (c & 1);
    v = (ss ? Ws : Wf)[i*192*64 + k*64 + p];
  } else {
    int p = (c-128) >> 1; bool ss = (c & 1);
    v = (ss ? Ws : Wf)[i*192*64 + (64+k)*64 + p];
  }
  Wcat[i*64*256 + k*256 + c] = v;
}

// ---------------- node transform: 32 nodes x 256 cols, prefetched weights ----------------
__global__ void k_ntrans(const float* __restrict__ x, const float* __restrict__ Wc,
                         float* __restrict__ ptab, float* __restrict__ qtab){
  __shared__ float xs[32*64];       // 8 KB
  int n0 = blockIdx.x * 32;         // 3125 blocks exact
  int t = threadIdx.x;              // 256
  ((float4*)xs)[t]       = ((const float4*)(x + (size_t)n0*64))[t];
  ((float4*)xs)[t + 256] = ((const float4*)(x + (size_t)n0*64))[t + 256];
  __syncthreads();
  int cg = t & 63, ng = t >> 6;     // 64 col-groups x 4 cols; 4 node-groups x 8 nodes
  float4 acc[8];
  #pragma unroll
  for (int i = 0; i < 8; i++) acc[i] = make_float4(0.f,0.f,0.f,0.f);
  const float* wp = Wc + 4*cg;
  const float* xp = xs + ng*8*64;
  float4 w[8];
  #pragma unroll
  for (int j = 0; j < 8; j++) w[j] = *(const float4*)(wp + j*256);
  for (int k = 0; k < 64; k += 8){
    float4 wn[8];
    int kn = (k + 8 < 64) ? k + 8 : 0;
    #pragma unroll
    for (int j = 0; j < 8; j++) wn[j] = *(const float4*)(wp + (kn+j)*256);
    #pragma unroll
    for (int h = 0; h < 2; h++){
      #pragma unroll
      for (int nn = 0; nn < 8; nn++){
        float4 xv = *(const float4*)(xp + nn*64 + k + h*4);
        fma4(acc[nn], xv.x, w[h*4+0]); fma4(acc[nn], xv.y, w[h*4+1]);
        fma4(acc[nn], xv.z, w[h*4+2]); fma4(acc[nn], xv.w, w[h*4+3]);
      }
    }
    #pragma unroll
    for (int j = 0; j < 8; j++) w[j] = wn[j];
  }
  #pragma unroll
  for (int nn = 0; nn < 8; nn++){
    int node = n0 + ng*8 + nn;
    if (cg < 32)
      *(float4*)(ptab + (size_t)node*128 + 4*cg) = acc[nn];
    else
      *(float4*)(qtab + (size_t)node*128 + 4*(cg-32)) = acc[nn];
  }
}

// ---------------- edge pass: wave per node, 4-edge pipelined ----------------
__global__ void k_edge(const float* __restrict__ ptab, const float* __restrict__ qtab,
                       const int* __restrict__ offs,
                       const int* __restrict__ stgt, const float* __restrict__ skey,
                       const float* __restrict__ Gt2, const float* __restrict__ lng,
                       const float* __restrict__ lnb, float* __restrict__ x){
  int wid  = (blockIdx.x*256 + threadIdx.x) >> 6;
  int lane = threadIdx.x & 63;
  int n = wid;
  float2 pq = *(const float2*)(ptab + (size_t)n*128 + 2*lane);
  float pf = pq.x, ps = pq.y;
  int j0 = offs[n], j1 = offs[n+1];
  float acc = 0.f;
  for (int jb = j0; jb < j1; jb += 64){
    int cnt = min(64, j1 - jb);
    int   t_l = (jb + lane < j1) ? stgt[jb + lane] : 0;
    float k_l = (jb + lane < j1) ? skey[jb + lane] : 0.f;
    for (int u = 0; u < cnt; u += 4){
      float2 qv[4];
      float4 gv[4];
      float fr[4];
      float okm[4];
      #pragma unroll
      for (int i = 0; i < 4; i++){
        int ui = u + i;
        okm[i] = (ui < cnt) ? 1.f : 0.f;
        int us = (ui < cnt) ? ui : (cnt - 1);
        int   tg  = __shfl(t_l, us, 64);
        float key = __shfl(k_l, us, 64);
        int idx = (int)key;
        fr[i] = key - (float)idx;
        qv[i] = *(const float2*)(qtab + (size_t)tg*128 + 2*lane);
        gv[i] = *(const float4*)(Gt2 + (size_t)idx*256 + 4*lane);
      }
      #pragma unroll
      for (int i = 0; i < 4; i++){
        float rf = fmaf(fr[i], gv[i].z - gv[i].x, gv[i].x);
        float rs = fmaf(fr[i], gv[i].w - gv[i].y, gv[i].y);
        float zf = pf + qv[i].x + rf;
        float zs = ps + qv[i].y + rs;
        acc = fmaf(sigmoid_f(zf) * softplus_f(zs), okm[i], acc);
      }
    }
  }
  float s1 = acc, s2 = acc*acc;
  #pragma unroll
  for (int o = 32; o > 0; o >>= 1){ s1 += __shfl_xor(s1, o, 64); s2 += __shfl_xor(s2, o, 64); }
  float mu  = s1 * (1.f/64.f);
  float var = s2 * (1.f/64.f) - mu*mu;
  float inv = rsqrtf(fmaxf(var, 0.f) + 1e-5f);
  float y = (acc - mu) * inv * lng[lane] + lnb[lane];
  x[(size_t)n*64 + lane] += y;
}

// ---------------- fused head with prefetched weights ----------------
__global__ void k_head(const float* __restrict__ x,
                       const float* __restrict__ W1, const float* __restrict__ b1,
                       const float* __restrict__ g1, const float* __restrict__ bt1,
                       const float* __restrict__ W2, const float* __restrict__ b2,
                       const float* __restrict__ g2, const float* __restrict__ bt2,
                       const float* __restrict__ Wout, const int* __restrict__ batch,
                       float* gsum, int* gcnt){
  __shared__ float xs[32*64];       // 8 KB
  __shared__ float hs[32*128];      // 16 KB
  int n0 = blockIdx.x * 32;         // 3125 blocks
  int t = threadIdx.x;              // 256
  ((float4*)xs)[t]       = ((const float4*)(x + (size_t)n0*64))[t];
  ((float4*)xs)[t + 256] = ((const float4*)(x + (size_t)n0*64))[t + 256];
  __syncthreads();
  int cg = t & 31, ng = t >> 5;     // 32 col-groups x 4 cols; 8 node-groups x 4 nodes

  // ---- layer 1: 64 -> 128, LN, softplus, into hs ----
  {
    float4 acc[4];
    #pragma unroll
    for (int i = 0; i < 4; i++) acc[i] = make_float4(0.f,0.f,0.f,0.f);
    const float* wp = W1 + 4*cg;
    const float* xp = xs + ng*4*64;
    float4 w[8];
    #pragma unroll
    for (int j = 0; j < 8; j++) w[j] = *(const float4*)(wp + j*128);
    for (int k = 0; k < 64; k += 8){
      float4 wn[8];
      int kn = (k + 8 < 64) ? k + 8 : 0;
      #pragma unroll
      for (int j = 0; j < 8; j++) wn[j] = *(const float4*)(wp + (kn+j)*128);
      #pragma unroll
      for (int h = 0; h < 2; h++){
        #pragma unroll
        for (int nn = 0; nn < 4; nn++){
          float4 xv = *(const float4*)(xp + nn*64 + k + h*4);
          fma4(acc[nn], xv.x, w[h*4+0]); fma4(acc[nn], xv.y, w[h*4+1]);
          fma4(acc[nn], xv.z, w[h*4+2]); fma4(acc[nn], xv.w, w[h*4+3]);
        }
      }
      #pragma unroll
      for (int j = 0; j < 8; j++) w[j] = wn[j];
    }
    float4 bv  = *(const float4*)(b1  + 4*cg);
    float4 gv  = *(const float4*)(g1  + 4*cg);
    float4 btv = *(const float4*)(bt1 + 4*cg);
    #pragma unroll
    for (int nn = 0; nn < 4; nn++){
      float4 v = acc[nn];
      v.x += bv.x; v.y += bv.y; v.z += bv.z; v.w += bv.w;
      float s1 = v.x + v.y + v.z + v.w;
      float s2 = v.x*v.x + v.y*v.y + v.z*v.z + v.w*v.w;
      #pragma unroll
      for (int o = 16; o > 0; o >>= 1){ s1 += __shfl_xor(s1, o, 64); s2 += __shfl_xor(s2, o, 64); }
      float mu  = s1 * (1.f/128.f);
      float var = s2 * (1.f/128.f) - mu*mu;
      float inv = rsqrtf(fmaxf(var, 0.f) + 1e-5f);
      float4 o4;
      o4.x = softplus_f((v.x - mu)*inv*gv.x + btv.x);
      o4.y = softplus_f((v.y - mu)*inv*gv.y + btv.y);
      o4.z = softplus_f((v.z - mu)*inv*gv.z + btv.z);
      o4.w = softplus_f((v.w - mu)*inv*gv.w + btv.w);
      *(float4*)(hs + (ng*4 + nn)*128 + 4*cg) = o4;
    }
  }
  __syncthreads();

  // ---- layer 2: 128 -> 128, LN, softplus, proj, segment sum ----
  {
    float4 acc[4];
    #pragma unroll
    for (int i = 0; i < 4; i++) acc[i] = make_float4(0.f,0.f,0.f,0.f);
    const float* wp = W2 + 4*cg;
    const float* hp = hs + ng*4*128;
    float4 w[8];
    #pragma unroll
    for (int j = 0; j < 8; j++) w[j] = *(const float4*)(wp + j*128);
    for (int k = 0; k < 128; k += 8){
      float4 wn[8];
      int kn = (k + 8 < 128) ? k + 8 : 0;
      #pragma unroll
      for (int j = 0; j < 8; j++) wn[j] = *(const float4*)(wp + (kn+j)*128);
      #pragma unroll
      for (int h = 0; h < 2; h++){
        #pragma unroll
        for (int nn = 0; nn < 4; nn++){
          float4 hv = *(const float4*)(hp + nn*128 + k + h*4);
          fma4(acc[nn], hv.x, w[h*4+0]); fma4(acc[nn], hv.y, w[h*4+1]);
          fma4(acc[nn], hv.z, w[h*4+2]); fma4(acc[nn], hv.w, w[h*4+3]);
        }
      }
      #pragma unroll
      for (int j = 0; j < 8; j++) w[j] = wn[j];
    }
    float4 bv  = *(const float4*)(b2  + 4*cg);
    float4 gv  = *(const float4*)(g2  + 4*cg);
    float4 btv = *(const float4*)(bt2 + 4*cg);
    float4 wo  = *(const float4*)(Wout + 4*cg);
    #pragma unroll
    for (int nn = 0; nn < 4; nn++){
      float4 v = acc[nn];
      v.x += bv.x; v.y += bv.y; v.z += bv.z; v.w += bv.w;
      float s1 = v.x + v.y + v.z + v.w;
      float s2 = v.x*v.x + v.y*v.y + v.z*v.z + v.w*v.w;
      #pragma unroll
      for (int o = 16; o > 0; o >>= 1){ s1 += __shfl_xor(s1, o, 64); s2 += __shfl_xor(s2, o, 64); }
      float mu  = s1 * (1.f/128.f);
      float var = s2 * (1.f/128.f) - mu*mu;
      float inv = rsqrtf(fmaxf(var, 0.f) + 1e-5f);
      float ev = softplus_f((v.x - mu)*inv*gv.x + btv.x) * wo.x
               + softplus_f((v.y - mu)*inv*gv.y + btv.y) * wo.y
               + softplus_f((v.z - mu)*inv*gv.z + btv.z) * wo.z
               + softplus_f((v.w - mu)*inv*gv.w + btv.w) * wo.w;
      #pragma unroll
      for (int o = 16; o > 0; o >>= 1) ev += __shfl_xor(ev, o, 64);
      if (cg == 0){
        int node = n0 + ng*4 + nn;
        int gr = batch[node];
        atomicAdd(&gsum[gr], ev);
        atomicAdd(&gcnt[gr], 1);
      }
    }
  }
}

// ---------------- final ----------------
__global__ void k_final(const float* __restrict__ gsum, const int* __restrict__ gcnt,
                        const float* __restrict__ bout, float* __restrict__ out){
  int g = threadIdx.x;
  if (g < NGRAPH)
    out[g] = gsum[g] / fmaxf((float)gcnt[g], 1.f) + bout[0];
}

extern "C" void kernel_launch(void* const* d_in, const int* in_sizes, int n_in,
                              void* d_out, int out_size, void* d_ws, size_t ws_size,
                              hipStream_t stream){
  const int*   numbers = (const int*)d_in[0];
  const int*   eidx    = (const int*)d_in[1];
  const float* elen    = (const float*)d_in[2];
  const int*   batch   = (const int*)d_in[3];
  const float* embed   = (const float*)d_in[4];
  const float* Wf      = (const float*)d_in[5];
  const float* bf      = (const float*)d_in[6];
  const float* Ws      = (const float*)d_in[7];
  const float* bs      = (const float*)d_in[8];
  const float* lng     = (const float*)d_in[9];
  const float* lnb     = (const float*)d_in[10];
  const float* W1      = (const float*)d_in[11];
  const float* b1      = (const float*)d_in[12];
  const float* g1      = (const float*)d_in[13];
  const float* bt1     = (const float*)d_in[14];
  const float* W2      = (const float*)d_in[15];
  const float* b2      = (const float*)d_in[16];
  const float* g2      = (const float*)d_in[17];
  const float* bt2     = (const float*)d_in[18];
  const float* Wout    = (const float*)d_in[19];
  const float* bout    = (const float*)d_in[20];
  const int* src = eidx;
  const int* tgt = eidx + NEDGES;

  float* x    = (float*)d_ws;                         // N*64
  float* ptab = x    + (size_t)NNODES*64;             // N*128
  float* qtab = ptab + (size_t)NNODES*128;            // N*128
  float* Gt   = qtab + (size_t)NNODES*128;            // 3*TBL*128
  float* Gt2  = Gt   + (size_t)3*TBL*128;             // 3*TBL*256
  float* Wcat = Gt2  + (size_t)3*TBL*256;             // 3*64*256
  float* skey = Wcat + (size_t)3*64*256;              // E
  int*   stgt = (int*)(skey + NEDGES);                // E
  int*   offs = stgt + NEDGES;                        // N+1
  int*   cur  = offs + NNODES + 1;                    // N
  int*   deg  = cur  + NNODES;                        // N
  int*   bsum = deg  + NNODES;                        // 128
  int*   bbase= bsum + 128;                           // 128
  float* gsum = (float*)(bbase + 128);                // 256
  int*   gcnt = (int*)(gsum + NGRAPH);                // 256
  float* out  = (float*)d_out;

  k_init  <<<(NNODES+255)/256, 256, 0, stream>>>(deg, gsum, gcnt);
  k_embed <<<(NNODES*64+255)/256, 256, 0, stream>>>(numbers, embed, x);

  k_hist   <<<(NEDGES+255)/256, 256, 0, stream>>>(src, deg);
  k_scan1  <<<NB1, 1024, 0, stream>>>(deg, offs, bsum);
  k_scan2  <<<1, 64, 0, stream>>>(bsum, bbase, offs);
  k_scan3  <<<(NNODES+255)/256, 256, 0, stream>>>(offs, bbase, cur);
  k_scatter<<<(NEDGES+255)/256, 256, 0, stream>>>(src, tgt, elen, cur, stgt, skey);

  k_gauss <<<3*TBL, 128, 0, stream>>>(Wf, bf, Ws, bs, Gt);
  k_gpack <<<3*TBL, 64, 0, stream>>>(Gt, Gt2);
  k_wcat  <<<(3*64*256+255)/256, 256, 0, stream>>>(Wf, Ws, Wcat);

  for (int i = 0; i < NCONV; i++){
    k_ntrans<<<NNODES/32, 256, 0, stream>>>(x, Wcat + (size_t)i*64*256, ptab, qtab);
    k_edge  <<<NNODES/4, 256, 0, stream>>>(ptab, qtab, offs, stgt, skey,
                                           Gt2 + (size_t)i*TBL*256,
                                           lng + i*64, lnb + i*64, x);
  }

  k_head<<<NNODES/32, 256, 0, stream>>>(x, W1, b1, g1, bt1,
                                        W2, b2, g2, bt2, Wout, batch, gsum, gcnt);
  k_final<<<1, 256, 0, stream>>>(gsum, gcnt, bout, out);
}

// Round 7
// 1058.320 us; speedup vs baseline: 1.3710x; 1.1893x over previous
//
#include <hip/hip_runtime.h>
#include <math.h>

#define NNODES 100000
#define NEDGES 1600000
#define NGRAPH 256
#define NCONV  3
#define TBL    2048
#define NB1    98          // ceil(100000/1024)
#define R_MIN_ 1.0f
#define R_MAX_ 6.0f

__device__ __forceinline__ float softplus_f(float x){
  return fmaxf(x, 0.f) + __logf(1.f + __expf(-fabsf(x)));
}
__device__ __forceinline__ float sigmoid_f(float x){
  return __builtin_amdgcn_rcpf(1.f + __expf(-x));
}
__device__ __forceinline__ void fma4(float4& a, float s, const float4 w){
  a.x = fmaf(s, w.x, a.x); a.y = fmaf(s, w.y, a.y);
  a.z = fmaf(s, w.z, a.z); a.w = fmaf(s, w.w, a.w);
}

// ---------------- init ----------------
__global__ void k_init(int* deg, float* gsum, int* gcnt){
  int i = blockIdx.x*256 + threadIdx.x;
  if (i < NNODES) deg[i] = 0;
  if (i < NGRAPH){ gsum[i] = 0.f; gcnt[i] = 0; }
}

// ---------------- embedding gather ----------------
__global__ void k_embed(const int* __restrict__ numbers, const float* __restrict__ embed,
                        float* __restrict__ x){
  int i = blockIdx.x*256 + threadIdx.x;
  if (i >= NNODES*64) return;
  int n = i >> 6, c = i & 63;
  x[i] = embed[numbers[n]*64 + c];
}

// ---------------- CSR build ----------------
__global__ void k_hist(const int* __restrict__ src, int* deg){
  int e = blockIdx.x*256 + threadIdx.x;
  if (e < NEDGES) atomicAdd(&deg[src[e]], 1);
}

__global__ void k_scan1(const int* __restrict__ deg, int* __restrict__ offs, int* __restrict__ bsum){
  __shared__ int s[1024];
  int n = blockIdx.x*1024 + threadIdx.x;
  int v = (n < NNODES) ? deg[n] : 0;
  s[threadIdx.x] = v;
  __syncthreads();
  for (int d = 1; d < 1024; d <<= 1){
    int t = (threadIdx.x >= d) ? s[threadIdx.x - d] : 0;
    __syncthreads();
    s[threadIdx.x] += t;
    __syncthreads();
  }
  int incl = s[threadIdx.x];
  if (n < NNODES) offs[n] = incl - v;
  if (threadIdx.x == 1023) bsum[blockIdx.x] = incl;
}

__global__ void k_scan2(const int* __restrict__ bsum, int* __restrict__ bbase, int* __restrict__ offs){
  if (blockIdx.x == 0 && threadIdx.x == 0){
    int run = 0;
    for (int b = 0; b < NB1; b++){ int t = bsum[b]; bbase[b] = run; run += t; }
    offs[NNODES] = NEDGES;
  }
}

__global__ void k_scan3(int* __restrict__ offs, const int* __restrict__ bbase, int* __restrict__ cur){
  int n = blockIdx.x*256 + threadIdx.x;
  if (n < NNODES){
    int o = offs[n] + bbase[n >> 10];
    offs[n] = o;
    cur[n]  = o;
  }
}

__global__ void k_scatter(const int* __restrict__ src, const int* __restrict__ tgt,
                          const float* __restrict__ elen, int* cur,
                          int* __restrict__ stgt, float* __restrict__ skey){
  int e = blockIdx.x*256 + threadIdx.x;
  if (e >= NEDGES) return;
  int s = src[e];
  int pos = atomicAdd(&cur[s], 1);
  stgt[pos] = tgt[e];
  float key = (elen[e] - R_MIN_) * ((float)(TBL-1)/(R_MAX_-R_MIN_));
  key = fminf(fmaxf(key, 0.f), (float)(TBL-1) - 1e-3f);
  skey[pos] = key;
}

// ---------------- Gaussian table ----------------
__global__ void k_gauss(const float* __restrict__ Wf, const float* __restrict__ bf,
                        const float* __restrict__ Ws, const float* __restrict__ bs,
                        float* __restrict__ Gt){
  __shared__ float attr[64];
  int bi = blockIdx.x;
  int i = bi / TBL, r = bi % TBL;
  int t = threadIdx.x;
  float d = R_MIN_ + (R_MAX_-R_MIN_) * (float)r / (float)(TBL-1);
  if (t < 64){
    float cj = 1.f + 5.f * (float)t / 63.f;
    float u = (d - cj) * (64.f/5.f);
    attr[t] = __expf(-0.5f*u*u);
  }
  __syncthreads();
  int c = t >> 1;
  bool sside = (t & 1);
  const float* W = (sside ? Ws : Wf) + i*192*64 + 128*64 + c;
  float acc = (sside ? bs : bf)[i*64 + c];
  #pragma unroll 8
  for (int j = 0; j < 64; j++) acc = fmaf(attr[j], W[j*64], acc);
  Gt[(i*TBL + r)*128 + t] = acc;
}

// ---------------- pack Gt rows r, r+1 into interleaved float4 table ----------------
__global__ void k_gpack(const float* __restrict__ Gt, float* __restrict__ Gt2){
  int bi = blockIdx.x;                 // 3*TBL
  int i = bi / TBL, r = bi % TBL;
  int l = threadIdx.x;                 // 0..63
  int r1 = (r + 1 < TBL) ? r + 1 : r;
  const float* g0 = Gt + ((size_t)i*TBL + r )*128;
  const float* g1 = Gt + ((size_t)i*TBL + r1)*128;
  float4 v;
  v.x = g0[2*l]; v.y = g0[2*l+1];
  v.z = g1[2*l]; v.w = g1[2*l+1];
  ((float4*)(Gt2 + ((size_t)i*TBL + r)*256))[l] = v;
}

// ---------------- Wcat pack ----------------
__global__ void k_wcat(const float* __restrict__ Wf, const float* __restrict__ Ws,
                       float* __restrict__ Wcat){
  int idx = blockIdx.x*256 + threadIdx.x;
  if (idx >= 3*64*256) return;
  int i = idx / (64*256);
  int rem = idx % (64*256);
  int k = rem / 256, c = rem % 256;
  float v;
  if (c < 128){
    int p = c >> 1; bool ss = (c & 1);
    v = (ss ? Ws : Wf)[i*192*64 + k*64 + p];
  } else {
    int p = (c-128) >> 1; bool ss = (c & 1);
    v = (ss ? Ws : Wf)[i*192*64 + (64+k)*64 + p];
  }
  Wcat[i*64*256 + k*256 + c] = v;
}

// ---------------- node transform: 32 nodes x 256 cols ----------------
__global__ void k_ntrans(const float* __restrict__ x, const float* __restrict__ Wc,
                         float* __restrict__ ptab, float* __restrict__ qtab){
  __shared__ float xs[32*64];       // 8 KB
  int n0 = blockIdx.x * 32;         // 3125 blocks exact
  int t = threadIdx.x;              // 256
  ((float4*)xs)[t]       = ((const float4*)(x + (size_t)n0*64))[t];
  ((float4*)xs)[t + 256] = ((const float4*)(x + (size_t)n0*64))[t + 256];
  __syncthreads();
  int cg = t & 63, ng = t >> 6;     // 64 col-groups x 4 cols; 4 node-groups x 8 nodes
  float4 acc[8];
  #pragma unroll
  for (int i = 0; i < 8; i++) acc[i] = make_float4(0.f,0.f,0.f,0.f);
  const float* wp = Wc + 4*cg;
  const float* xp = xs + ng*8*64;
  #pragma unroll 2
  for (int k = 0; k < 64; k += 4){
    float4 w0 = *(const float4*)(wp + (k+0)*256);
    float4 w1 = *(const float4*)(wp + (k+1)*256);
    float4 w2 = *(const float4*)(wp + (k+2)*256);
    float4 w3 = *(const float4*)(wp + (k+3)*256);
    #pragma unroll
    for (int nn = 0; nn < 8; nn++){
      float4 xv = *(const float4*)(xp + nn*64 + k);
      fma4(acc[nn], xv.x, w0); fma4(acc[nn], xv.y, w1);
      fma4(acc[nn], xv.z, w2); fma4(acc[nn], xv.w, w3);
    }
  }
  #pragma unroll
  for (int nn = 0; nn < 8; nn++){
    int node = n0 + ng*8 + nn;
    if (cg < 32)
      *(float4*)(ptab + (size_t)node*128 + 4*cg) = acc[nn];
    else
      *(float4*)(qtab + (size_t)node*128 + 4*(cg-32)) = acc[nn];
  }
}

// ---------------- edge pass: wave per node, 8-edge pipelined ----------------
__global__ void k_edge(const float* __restrict__ ptab, const float* __restrict__ qtab,
                       const int* __restrict__ offs,
                       const int* __restrict__ stgt, const float* __restrict__ skey,
                       const float* __restrict__ Gt2, const float* __restrict__ lng,
                       const float* __restrict__ lnb, float* __restrict__ x){
  int wid  = (blockIdx.x*256 + threadIdx.x) >> 6;
  int lane = threadIdx.x & 63;
  int n = wid;
  float2 pq = *(const float2*)(ptab + (size_t)n*128 + 2*lane);
  float pf = pq.x, ps = pq.y;
  int j0 = offs[n], j1 = offs[n+1];
  float acc = 0.f;
  for (int jb = j0; jb < j1; jb += 64){
    int cnt = min(64, j1 - jb);
    int   t_l = (jb + lane < j1) ? stgt[jb + lane] : 0;
    float k_l = (jb + lane < j1) ? skey[jb + lane] : 0.f;
    for (int u = 0; u < cnt; u += 8){
      float2 qv[8];
      float4 gv[8];
      float fr[8];
      float okm[8];
      #pragma unroll
      for (int i = 0; i < 8; i++){
        int ui = u + i;
        okm[i] = (ui < cnt) ? 1.f : 0.f;
        int us = (ui < cnt) ? ui : (cnt - 1);
        int   tg  = __shfl(t_l, us, 64);
        float key = __shfl(k_l, us, 64);
        int idx = (int)key;
        fr[i] = key - (float)idx;
        qv[i] = *(const float2*)(qtab + (size_t)tg*128 + 2*lane);
        gv[i] = *(const float4*)(Gt2 + (size_t)idx*256 + 4*lane);
      }
      #pragma unroll
      for (int i = 0; i < 8; i++){
        float rf = fmaf(fr[i], gv[i].z - gv[i].x, gv[i].x);
        float rs = fmaf(fr[i], gv[i].w - gv[i].y, gv[i].y);
        float zf = pf + qv[i].x + rf;
        float zs = ps + qv[i].y + rs;
        acc = fmaf(sigmoid_f(zf) * softplus_f(zs), okm[i], acc);
      }
    }
  }
  float s1 = acc, s2 = acc*acc;
  #pragma unroll
  for (int o = 32; o > 0; o >>= 1){ s1 += __shfl_xor(s1, o, 64); s2 += __shfl_xor(s2, o, 64); }
  float mu  = s1 * (1.f/64.f);
  float var = s2 * (1.f/64.f) - mu*mu;
  float inv = rsqrtf(fmaxf(var, 0.f) + 1e-5f);
  float y = (acc - mu) * inv * lng[lane] + lnb[lane];
  x[(size_t)n*64 + lane] += y;
}

// ---------------- fused head; segmented block reduction for the segment sum ----------------
__global__ void k_head(const float* __restrict__ x,
                       const float* __restrict__ W1, const float* __restrict__ b1,
                       const float* __restrict__ g1, const float* __restrict__ bt1,
                       const float* __restrict__ W2, const float* __restrict__ b2,
                       const float* __restrict__ g2, const float* __restrict__ bt2,
                       const float* __restrict__ Wout, const int* __restrict__ batch,
                       float* gsum, int* gcnt){
  __shared__ float xs[32*64];       // 8 KB
  __shared__ float hs[32*128];      // 16 KB
  __shared__ float es[32];
  int n0 = blockIdx.x * 32;         // 3125 blocks
  int t = threadIdx.x;              // 256
  ((float4*)xs)[t]       = ((const float4*)(x + (size_t)n0*64))[t];
  ((float4*)xs)[t + 256] = ((const float4*)(x + (size_t)n0*64))[t + 256];
  __syncthreads();
  int cg = t & 31, ng = t >> 5;     // 32 col-groups x 4 cols; 8 node-groups x 4 nodes

  // ---- layer 1: 64 -> 128, LN, softplus, into hs ----
  {
    float4 acc[4];
    #pragma unroll
    for (int i = 0; i < 4; i++) acc[i] = make_float4(0.f,0.f,0.f,0.f);
    const float* wp = W1 + 4*cg;
    const float* xp = xs + ng*4*64;
    #pragma unroll 2
    for (int k = 0; k < 64; k += 4){
      float4 w0 = *(const float4*)(wp + (k+0)*128);
      float4 w1 = *(const float4*)(wp + (k+1)*128);
      float4 w2 = *(const float4*)(wp + (k+2)*128);
      float4 w3 = *(const float4*)(wp + (k+3)*128);
      #pragma unroll
      for (int nn = 0; nn < 4; nn++){
        float4 xv = *(const float4*)(xp + nn*64 + k);
        fma4(acc[nn], xv.x, w0); fma4(acc[nn], xv.y, w1);
        fma4(acc[nn], xv.z, w2); fma4(acc[nn], xv.w, w3);
      }
    }
    float4 bv  = *(const float4*)(b1  + 4*cg);
    float4 gv  = *(const float4*)(g1  + 4*cg);
    float4 btv = *(const float4*)(bt1 + 4*cg);
    #pragma unroll
    for (int nn = 0; nn < 4; nn++){
      float4 v = acc[nn];
      v.x += bv.x; v.y += bv.y; v.z += bv.z; v.w += bv.w;
      float s1 = v.x + v.y + v.z + v.w;
      float s2 = v.x*v.x + v.y*v.y + v.z*v.z + v.w*v.w;
      #pragma unroll
      for (int o = 16; o > 0; o >>= 1){ s1 += __shfl_xor(s1, o, 64); s2 += __shfl_xor(s2, o, 64); }
      float mu  = s1 * (1.f/128.f);
      float var = s2 * (1.f/128.f) - mu*mu;
      float inv = rsqrtf(fmaxf(var, 0.f) + 1e-5f);
      float4 o4;
      o4.x = softplus_f((v.x - mu)*inv*gv.x + btv.x);
      o4.y = softplus_f((v.y - mu)*inv*gv.y + btv.y);
      o4.z = softplus_f((v.z - mu)*inv*gv.z + btv.z);
      o4.w = softplus_f((v.w - mu)*inv*gv.w + btv.w);
      *(float4*)(hs + (ng*4 + nn)*128 + 4*cg) = o4;
    }
  }
  __syncthreads();

  // ---- layer 2: 128 -> 128, LN, softplus, proj -> per-node energy in es ----
  {
    float4 acc[4];
    #pragma unroll
    for (int i = 0; i < 4; i++) acc[i] = make_float4(0.f,0.f,0.f,0.f);
    const float* wp = W2 + 4*cg;
    const float* hp = hs + ng*4*128;
    #pragma unroll 2
    for (int k = 0; k < 128; k += 4){
      float4 w0 = *(const float4*)(wp + (k+0)*128);
      float4 w1 = *(const float4*)(wp + (k+1)*128);
      float4 w2 = *(const float4*)(wp + (k+2)*128);
      float4 w3 = *(const float4*)(wp + (k+3)*128);
      #pragma unroll
      for (int nn = 0; nn < 4; nn++){
        float4 hv = *(const float4*)(hp + nn*128 + k);
        fma4(acc[nn], hv.x, w0); fma4(acc[nn], hv.y, w1);
        fma4(acc[nn], hv.z, w2); fma4(acc[nn], hv.w, w3);
      }
    }
    float4 bv  = *(const float4*)(b2  + 4*cg);
    float4 gv  = *(const float4*)(g2  + 4*cg);
    float4 btv = *(const float4*)(bt2 + 4*cg);
    float4 wo  = *(const float4*)(Wout + 4*cg);
    #pragma unroll
    for (int nn = 0; nn < 4; nn++){
      float4 v = acc[nn];
      v.x += bv.x; v.y += bv.y; v.z += bv.z; v.w += bv.w;
      float s1 = v.x + v.y + v.z + v.w;
      float s2 = v.x*v.x + v.y*v.y + v.z*v.z + v.w*v.w;
      #pragma unroll
      for (int o = 16; o > 0; o >>= 1){ s1 += __shfl_xor(s1, o, 64); s2 += __shfl_xor(s2, o, 64); }
      float mu  = s1 * (1.f/128.f);
      float var = s2 * (1.f/128.f) - mu*mu;
      float inv = rsqrtf(fmaxf(var, 0.f) + 1e-5f);
      float ev = softplus_f((v.x - mu)*inv*gv.x + btv.x) * wo.x
               + softplus_f((v.y - mu)*inv*gv.y + btv.y) * wo.y
               + softplus_f((v.z - mu)*inv*gv.z + btv.z) * wo.z
               + softplus_f((v.w - mu)*inv*gv.w + btv.w) * wo.w;
      #pragma unroll
      for (int o = 16; o > 0; o >>= 1) ev += __shfl_xor(ev, o, 64);
      if (cg == 0) es[ng*4 + nn] = ev;
    }
  }
  __syncthreads();

  // ---- segmented reduction over the sorted 32-node tile: ~1-3 atomics/block ----
  if (t < 32){
    int node = n0 + t;
    int g = batch[node];
    bool head = (t == 0) || (batch[node-1] != g);
    if (head){
      float s = 0.f; int c = 0;
      int j = t;
      while (j < 32 && batch[n0+j] == g){ s += es[j]; c++; j++; }
      atomicAdd(&gsum[g], s);
      atomicAdd(&gcnt[g], c);
    }
  }
}

// ---------------- final ----------------
__global__ void k_final(const float* __restrict__ gsum, const int* __restrict__ gcnt,
                        const float* __restrict__ bout, float* __restrict__ out){
  int g = threadIdx.x;
  if (g < NGRAPH)
    out[g] = gsum[g] / fmaxf((float)gcnt[g], 1.f) + bout[0];
}

extern "C" void kernel_launch(void* const* d_in, const int* in_sizes, int n_in,
                              void* d_out, int out_size, void* d_ws, size_t ws_size,
                              hipStream_t stream){
  const int*   numbers = (const int*)d_in[0];
  const int*   eidx    = (const int*)d_in[1];
  const float* elen    = (const float*)d_in[2];
  const int*   batch   = (const int*)d_in[3];
  const float* embed   = (const float*)d_in[4];
  const float* Wf      = (const float*)d_in[5];
  const float* bf      = (const float*)d_in[6];
  const float* Ws      = (const float*)d_in[7];
  const float* bs      = (const float*)d_in[8];
  const float* lng     = (const float*)d_in[9];
  const float* lnb     = (const float*)d_in[10];
  const float* W1      = (const float*)d_in[11];
  const float* b1      = (const float*)d_in[12];
  const float* g1      = (const float*)d_in[13];
  const float* bt1     = (const float*)d_in[14];
  const float* W2      = (const float*)d_in[15];
  const float* b2      = (const float*)d_in[16];
  const float* g2      = (const float*)d_in[17];
  const float* bt2     = (const float*)d_in[18];
  const float* Wout    = (const float*)d_in[19];
  const float* bout    = (const float*)d_in[20];
  const int* src = eidx;
  const int* tgt = eidx + NEDGES;

  float* x    = (float*)d_ws;                         // N*64
  float* ptab = x    + (size_t)NNODES*64;             // N*128
  float* qtab = ptab + (size_t)NNODES*128;            // N*128
  float* Gt   = qtab + (size_t)NNODES*128;            // 3*TBL*128
  float* Gt2  = Gt   + (size_t)3*TBL*128;             // 3*TBL*256
  float* Wcat = Gt2  + (size_t)3*TBL*256;             // 3*64*256
  float* skey = Wcat + (size_t)3*64*256;              // E
  int*   stgt = (int*)(skey + NEDGES);                // E
  int*   offs = stgt + NEDGES;                        // N+1
  int*   cur  = offs + NNODES + 1;                    // N
  int*   deg  = cur  + NNODES;                        // N
  int*   bsum = deg  + NNODES;                        // 128
  int*   bbase= bsum + 128;                           // 128
  float* gsum = (float*)(bbase + 128);                // 256
  int*   gcnt = (int*)(gsum + NGRAPH);                // 256
  float* out  = (float*)d_out;

  k_init  <<<(NNODES+255)/256, 256, 0, stream>>>(deg, gsum, gcnt);
  k_embed <<<(NNODES*64+255)/256, 256, 0, stream>>>(numbers, embed, x);

  k_hist   <<<(NEDGES+255)/256, 256, 0, stream>>>(src, deg);
  k_scan1  <<<NB1, 1024, 0, stream>>>(deg, offs, bsum);
  k_scan2  <<<1, 64, 0, stream>>>(bsum, bbase, offs);
  k_scan3  <<<(NNODES+255)/256, 256, 0, stream>>>(offs, bbase, cur);
  k_scatter<<<(NEDGES+255)/256, 256, 0, stream>>>(src, tgt, elen, cur, stgt, skey);

  k_gauss <<<3*TBL, 128, 0, stream>>>(Wf, bf, Ws, bs, Gt);
  k_gpack <<<3*TBL, 64, 0, stream>>>(Gt, Gt2);
  k_wcat  <<<(3*64*256+255)/256, 256, 0, stream>>>(Wf, Ws, Wcat);

  for (int i = 0; i < NCONV; i++){
    k_ntrans<<<NNODES/32, 256, 0, stream>>>(x, Wcat + (size_t)i*64*256, ptab, qtab);
    k_edge  <<<NNODES/4, 256, 0, stream>>>(ptab, qtab, offs, stgt, skey,
                                           Gt2 + (size_t)i*TBL*256,
                                           lng + i*64, lnb + i*64, x);
  }

  k_head<<<NNODES/32, 256, 0, stream>>>(x, W1, b1, g1, bt1,
                                        W2, b2, g2, bt2, Wout, batch, gsum, gcnt);
  k_final<<<1, 256, 0, stream>>>(gsum, gcnt, bout, out);
}

// Round 8
// 928.467 us; speedup vs baseline: 1.5628x; 1.1399x over previous
//
#include <hip/hip_runtime.h>
#include <hip/hip_fp16.h>
#include <math.h>

#define NNODES 100000
#define NEDGES 1600000
#define NGRAPH 256
#define NCONV  3
#define TBL    2048
#define NB1    98          // ceil(100000/1024)
#define R_MIN_ 1.0f
#define R_MAX_ 6.0f

__device__ __forceinline__ float softplus_f(float x){
  return fmaxf(x, 0.f) + __logf(1.f + __expf(-fabsf(x)));
}
__device__ __forceinline__ float sigmoid_f(float x){
  return __builtin_amdgcn_rcpf(1.f + __expf(-x));
}
__device__ __forceinline__ void fma4(float4& a, float s, const float4 w){
  a.x = fmaf(s, w.x, a.x); a.y = fmaf(s, w.y, a.y);
  a.z = fmaf(s, w.z, a.z); a.w = fmaf(s, w.w, a.w);
}

// ---------------- init ----------------
__global__ void k_init(int* deg, float* gsum, int* gcnt){
  int i = blockIdx.x*256 + threadIdx.x;
  if (i < NNODES) deg[i] = 0;
  if (i < NGRAPH){ gsum[i] = 0.f; gcnt[i] = 0; }
}

// ---------------- embedding gather ----------------
__global__ void k_embed(const int* __restrict__ numbers, const float* __restrict__ embed,
                        float* __restrict__ x){
  int i = blockIdx.x*256 + threadIdx.x;
  if (i >= NNODES*64) return;
  int n = i >> 6, c = i & 63;
  x[i] = embed[numbers[n]*64 + c];
}

// ---------------- CSR build ----------------
__global__ void k_hist(const int* __restrict__ src, int* deg){
  int e = blockIdx.x*256 + threadIdx.x;
  if (e < NEDGES) atomicAdd(&deg[src[e]], 1);
}

__global__ void k_scan1(const int* __restrict__ deg, int* __restrict__ offs, int* __restrict__ bsum){
  __shared__ int s[1024];
  int n = blockIdx.x*1024 + threadIdx.x;
  int v = (n < NNODES) ? deg[n] : 0;
  s[threadIdx.x] = v;
  __syncthreads();
  for (int d = 1; d < 1024; d <<= 1){
    int t = (threadIdx.x >= d) ? s[threadIdx.x - d] : 0;
    __syncthreads();
    s[threadIdx.x] += t;
    __syncthreads();
  }
  int incl = s[threadIdx.x];
  if (n < NNODES) offs[n] = incl - v;
  if (threadIdx.x == 1023) bsum[blockIdx.x] = incl;
}

__global__ void k_scan2(const int* __restrict__ bsum, int* __restrict__ bbase, int* __restrict__ offs){
  if (blockIdx.x == 0 && threadIdx.x == 0){
    int run = 0;
    for (int b = 0; b < NB1; b++){ int t = bsum[b]; bbase[b] = run; run += t; }
    offs[NNODES] = NEDGES;
  }
}

__global__ void k_scan3(int* __restrict__ offs, const int* __restrict__ bbase, int* __restrict__ cur){
  int n = blockIdx.x*256 + threadIdx.x;
  if (n < NNODES){
    int o = offs[n] + bbase[n >> 10];
    offs[n] = o;
    cur[n]  = o;
  }
}

__global__ void k_scatter(const int* __restrict__ src, const int* __restrict__ tgt,
                          const float* __restrict__ elen, int* cur,
                          int2* __restrict__ ep){
  int e = blockIdx.x*256 + threadIdx.x;
  if (e >= NEDGES) return;
  int s = src[e];
  int pos = atomicAdd(&cur[s], 1);
  float key = (elen[e] - R_MIN_) * ((float)(TBL-1)/(R_MAX_-R_MIN_));
  key = fminf(fmaxf(key, 0.f), (float)(TBL-1) - 1e-3f);
  ep[pos] = make_int2(tgt[e], __float_as_int(key));
}

// ---------------- Gaussian table ----------------
__global__ void k_gauss(const float* __restrict__ Wf, const float* __restrict__ bf,
                        const float* __restrict__ Ws, const float* __restrict__ bs,
                        float* __restrict__ Gt){
  __shared__ float attr[64];
  int bi = blockIdx.x;
  int i = bi / TBL, r = bi % TBL;
  int t = threadIdx.x;
  float d = R_MIN_ + (R_MAX_-R_MIN_) * (float)r / (float)(TBL-1);
  if (t < 64){
    float cj = 1.f + 5.f * (float)t / 63.f;
    float u = (d - cj) * (64.f/5.f);
    attr[t] = __expf(-0.5f*u*u);
  }
  __syncthreads();
  int c = t >> 1;
  bool sside = (t & 1);
  const float* W = (sside ? Ws : Wf) + i*192*64 + 128*64 + c;
  float acc = (sside ? bs : bf)[i*64 + c];
  #pragma unroll 8
  for (int j = 0; j < 64; j++) acc = fmaf(attr[j], W[j*64], acc);
  Gt[(i*TBL + r)*128 + t] = acc;
}

// ---------------- pack Gt rows r, r+1 into interleaved float4 table ----------------
__global__ void k_gpack(const float* __restrict__ Gt, float* __restrict__ Gt2){
  int bi = blockIdx.x;                 // 3*TBL
  int i = bi / TBL, r = bi % TBL;
  int l = threadIdx.x;                 // 0..63
  int r1 = (r + 1 < TBL) ? r + 1 : r;
  const float* g0 = Gt + ((size_t)i*TBL + r )*128;
  const float* g1 = Gt + ((size_t)i*TBL + r1)*128;
  float4 v;
  v.x = g0[2*l]; v.y = g0[2*l+1];
  v.z = g1[2*l]; v.w = g1[2*l+1];
  ((float4*)(Gt2 + ((size_t)i*TBL + r)*256))[l] = v;
}

// ---------------- Wcat pack ----------------
__global__ void k_wcat(const float* __restrict__ Wf, const float* __restrict__ Ws,
                       float* __restrict__ Wcat){
  int idx = blockIdx.x*256 + threadIdx.x;
  if (idx >= 3*64*256) return;
  int i = idx / (64*256);
  int rem = idx % (64*256);
  int k = rem / 256, c = rem % 256;
  float v;
  if (c < 128){
    int p = c >> 1; bool ss = (c & 1);
    v = (ss ? Ws : Wf)[i*192*64 + k*64 + p];
  } else {
    int p = (c-128) >> 1; bool ss = (c & 1);
    v = (ss ? Ws : Wf)[i*192*64 + (64+k)*64 + p];
  }
  Wcat[i*64*256 + k*256 + c] = v;
}

// ---------------- node transform: 32 nodes x 256 cols; q side stored fp16 ----------------
__global__ void k_ntrans(const float* __restrict__ x, const float* __restrict__ Wc,
                         float* __restrict__ ptab, __half2* __restrict__ qh){
  __shared__ float xs[32*64];       // 8 KB
  int n0 = blockIdx.x * 32;         // 3125 blocks exact
  int t = threadIdx.x;              // 256
  ((float4*)xs)[t]       = ((const float4*)(x + (size_t)n0*64))[t];
  ((float4*)xs)[t + 256] = ((const float4*)(x + (size_t)n0*64))[t + 256];
  __syncthreads();
  int cg = t & 63, ng = t >> 6;     // 64 col-groups x 4 cols; 4 node-groups x 8 nodes
  float4 acc[8];
  #pragma unroll
  for (int i = 0; i < 8; i++) acc[i] = make_float4(0.f,0.f,0.f,0.f);
  const float* wp = Wc + 4*cg;
  const float* xp = xs + ng*8*64;
  #pragma unroll 2
  for (int k = 0; k < 64; k += 4){
    float4 w0 = *(const float4*)(wp + (k+0)*256);
    float4 w1 = *(const float4*)(wp + (k+1)*256);
    float4 w2 = *(const float4*)(wp + (k+2)*256);
    float4 w3 = *(const float4*)(wp + (k+3)*256);
    #pragma unroll
    for (int nn = 0; nn < 8; nn++){
      float4 xv = *(const float4*)(xp + nn*64 + k);
      fma4(acc[nn], xv.x, w0); fma4(acc[nn], xv.y, w1);
      fma4(acc[nn], xv.z, w2); fma4(acc[nn], xv.w, w3);
    }
  }
  #pragma unroll
  for (int nn = 0; nn < 8; nn++){
    int node = n0 + ng*8 + nn;
    if (cg < 32){
      *(float4*)(ptab + (size_t)node*128 + 4*cg) = acc[nn];
    } else {
      __half2 h0 = __float22half2_rn(make_float2(acc[nn].x, acc[nn].y));
      __half2 h1 = __float22half2_rn(make_float2(acc[nn].z, acc[nn].w));
      __half2* qp = qh + (size_t)node*64 + 2*(cg-32);
      qp[0] = h0; qp[1] = h1;
    }
  }
}

// ---------------- edge pass: wave per node, scalar edge metadata, fp16 q gather ----------------
__global__ void k_edge(const float* __restrict__ ptab, const __half2* __restrict__ qh,
                       const int* __restrict__ offs, const int2* __restrict__ ep,
                       const float* __restrict__ Gt2, const float* __restrict__ lng,
                       const float* __restrict__ lnb, float* __restrict__ x){
  int wid  = (blockIdx.x*256 + threadIdx.x) >> 6;
  int lane = threadIdx.x & 63;
  int n = wid;
  float2 pq = *(const float2*)(ptab + (size_t)n*128 + 2*lane);
  float pf = pq.x, ps = pq.y;
  int j0 = __builtin_amdgcn_readfirstlane(offs[n]);
  int j1 = __builtin_amdgcn_readfirstlane(offs[n+1]);
  float acc = 0.f;
  int u = j0;
  for (; u + 8 <= j1; u += 8){
    float2 qv[8]; float4 gv[8]; float fr[8];
    #pragma unroll
    for (int i = 0; i < 8; i++){
      int2 e = ep[u + i];
      int tg = e.x;
      float key = __int_as_float(e.y);
      int idx = (int)key;
      fr[i] = key - (float)idx;
      qv[i] = __half22float2(qh[(size_t)tg*64 + lane]);
      gv[i] = *(const float4*)(Gt2 + (size_t)idx*256 + 4*lane);
    }
    #pragma unroll
    for (int i = 0; i < 8; i++){
      float rf = fmaf(fr[i], gv[i].z - gv[i].x, gv[i].x);
      float rs = fmaf(fr[i], gv[i].w - gv[i].y, gv[i].y);
      acc = fmaf(sigmoid_f(pf + qv[i].x + rf), softplus_f(ps + qv[i].y + rs), acc);
    }
  }
  for (; u < j1; u++){
    int2 e = ep[u];
    int tg = e.x;
    float key = __int_as_float(e.y);
    int idx = (int)key;
    float fr0 = key - (float)idx;
    float2 qv = __half22float2(qh[(size_t)tg*64 + lane]);
    float4 gv = *(const float4*)(Gt2 + (size_t)idx*256 + 4*lane);
    float rf = fmaf(fr0, gv.z - gv.x, gv.x);
    float rs = fmaf(fr0, gv.w - gv.y, gv.y);
    acc = fmaf(sigmoid_f(pf + qv.x + rf), softplus_f(ps + qv.y + rs), acc);
  }
  float s1 = acc, s2 = acc*acc;
  #pragma unroll
  for (int o = 32; o > 0; o >>= 1){ s1 += __shfl_xor(s1, o, 64); s2 += __shfl_xor(s2, o, 64); }
  float mu  = s1 * (1.f/64.f);
  float var = s2 * (1.f/64.f) - mu*mu;
  float inv = rsqrtf(fmaxf(var, 0.f) + 1e-5f);
  float y = (acc - mu) * inv * lng[lane] + lnb[lane];
  x[(size_t)n*64 + lane] += y;
}

// ---------------- fused head; segmented block reduction for the segment sum ----------------
__global__ void k_head(const float* __restrict__ x,
                       const float* __restrict__ W1, const float* __restrict__ b1,
                       const float* __restrict__ g1, const float* __restrict__ bt1,
                       const float* __restrict__ W2, const float* __restrict__ b2,
                       const float* __restrict__ g2, const float* __restrict__ bt2,
                       const float* __restrict__ Wout, const int* __restrict__ batch,
                       float* gsum, int* gcnt){
  __shared__ float xs[32*64];       // 8 KB
  __shared__ float hs[32*128];      // 16 KB
  __shared__ float es[32];
  int n0 = blockIdx.x * 32;         // 3125 blocks
  int t = threadIdx.x;              // 256
  ((float4*)xs)[t]       = ((const float4*)(x + (size_t)n0*64))[t];
  ((float4*)xs)[t + 256] = ((const float4*)(x + (size_t)n0*64))[t + 256];
  __syncthreads();
  int cg = t & 31, ng = t >> 5;     // 32 col-groups x 4 cols; 8 node-groups x 4 nodes

  // ---- layer 1: 64 -> 128, LN, softplus, into hs ----
  {
    float4 acc[4];
    #pragma unroll
    for (int i = 0; i < 4; i++) acc[i] = make_float4(0.f,0.f,0.f,0.f);
    const float* wp = W1 + 4*cg;
    const float* xp = xs + ng*4*64;
    #pragma unroll 2
    for (int k = 0; k < 64; k += 4){
      float4 w0 = *(const float4*)(wp + (k+0)*128);
      float4 w1 = *(const float4*)(wp + (k+1)*128);
      float4 w2 = *(const float4*)(wp + (k+2)*128);
      float4 w3 = *(const float4*)(wp + (k+3)*128);
      #pragma unroll
      for (int nn = 0; nn < 4; nn++){
        float4 xv = *(const float4*)(xp + nn*64 + k);
        fma4(acc[nn], xv.x, w0); fma4(acc[nn], xv.y, w1);
        fma4(acc[nn], xv.z, w2); fma4(acc[nn], xv.w, w3);
      }
    }
    float4 bv  = *(const float4*)(b1  + 4*cg);
    float4 gv  = *(const float4*)(g1  + 4*cg);
    float4 btv = *(const float4*)(bt1 + 4*cg);
    #pragma unroll
    for (int nn = 0; nn < 4; nn++){
      float4 v = acc[nn];
      v.x += bv.x; v.y += bv.y; v.z += bv.z; v.w += bv.w;
      float s1 = v.x + v.y + v.z + v.w;
      float s2 = v.x*v.x + v.y*v.y + v.z*v.z + v.w*v.w;
      #pragma unroll
      for (int o = 16; o > 0; o >>= 1){ s1 += __shfl_xor(s1, o, 64); s2 += __shfl_xor(s2, o, 64); }
      float mu  = s1 * (1.f/128.f);
      float var = s2 * (1.f/128.f) - mu*mu;
      float inv = rsqrtf(fmaxf(var, 0.f) + 1e-5f);
      float4 o4;
      o4.x = softplus_f((v.x - mu)*inv*gv.x + btv.x);
      o4.y = softplus_f((v.y - mu)*inv*gv.y + btv.y);
      o4.z = softplus_f((v.z - mu)*inv*gv.z + btv.z);
      o4.w = softplus_f((v.w - mu)*inv*gv.w + btv.w);
      *(float4*)(hs + (ng*4 + nn)*128 + 4*cg) = o4;
    }
  }
  __syncthreads();

  // ---- layer 2: 128 -> 128, LN, softplus, proj -> per-node energy in es ----
  {
    float4 acc[4];
    #pragma unroll
    for (int i = 0; i < 4; i++) acc[i] = make_float4(0.f,0.f,0.f,0.f);
    const float* wp = W2 + 4*cg;
    const float* hp = hs + ng*4*128;
    #pragma unroll 2
    for (int k = 0; k < 128; k += 4){
      float4 w0 = *(const float4*)(wp + (k+0)*128);
      float4 w1 = *(const float4*)(wp + (k+1)*128);
      float4 w2 = *(const float4*)(wp + (k+2)*128);
      float4 w3 = *(const float4*)(wp + (k+3)*128);
      #pragma unroll
      for (int nn = 0; nn < 4; nn++){
        float4 hv = *(const float4*)(hp + nn*128 + k);
        fma4(acc[nn], hv.x, w0); fma4(acc[nn], hv.y, w1);
        fma4(acc[nn], hv.z, w2); fma4(acc[nn], hv.w, w3);
      }
    }
    float4 bv  = *(const float4*)(b2  + 4*cg);
    float4 gv  = *(const float4*)(g2  + 4*cg);
    float4 btv = *(const float4*)(bt2 + 4*cg);
    float4 wo  = *(const float4*)(Wout + 4*cg);
    #pragma unroll
    for (int nn = 0; nn < 4; nn++){
      float4 v = acc[nn];
      v.x += bv.x; v.y += bv.y; v.z += bv.z; v.w += bv.w;
      float s1 = v.x + v.y + v.z + v.w;
      float s2 = v.x*v.x + v.y*v.y + v.z*v.z + v.w*v.w;
      #pragma unroll
      for (int o = 16; o > 0; o >>= 1){ s1 += __shfl_xor(s1, o, 64); s2 += __shfl_xor(s2, o, 64); }
      float mu  = s1 * (1.f/128.f);
      float var = s2 * (1.f/128.f) - mu*mu;
      float inv = rsqrtf(fmaxf(var, 0.f) + 1e-5f);
      float ev = softplus_f((v.x - mu)*inv*gv.x + btv.x) * wo.x
               + softplus_f((v.y - mu)*inv*gv.y + btv.y) * wo.y
               + softplus_f((v.z - mu)*inv*gv.z + btv.z) * wo.z
               + softplus_f((v.w - mu)*inv*gv.w + btv.w) * wo.w;
      #pragma unroll
      for (int o = 16; o > 0; o >>= 1) ev += __shfl_xor(ev, o, 64);
      if (cg == 0) es[ng*4 + nn] = ev;
    }
  }
  __syncthreads();

  // ---- segmented reduction over the sorted 32-node tile: ~1-3 atomics/block ----
  if (t < 32){
    int node = n0 + t;
    int g = batch[node];
    bool head = (t == 0) || (batch[node-1] != g);
    if (head){
      float s = 0.f; int c = 0;
      int j = t;
      while (j < 32 && batch[n0+j] == g){ s += es[j]; c++; j++; }
      atomicAdd(&gsum[g], s);
      atomicAdd(&gcnt[g], c);
    }
  }
}

// ---------------- final ----------------
__global__ void k_final(const float* __restrict__ gsum, const int* __restrict__ gcnt,
                        const float* __restrict__ bout, float* __restrict__ out){
  int g = threadIdx.x;
  if (g < NGRAPH)
    out[g] = gsum[g] / fmaxf((float)gcnt[g], 1.f) + bout[0];
}

extern "C" void kernel_launch(void* const* d_in, const int* in_sizes, int n_in,
                              void* d_out, int out_size, void* d_ws, size_t ws_size,
                              hipStream_t stream){
  const int*   numbers = (const int*)d_in[0];
  const int*   eidx    = (const int*)d_in[1];
  const float* elen    = (const float*)d_in[2];
  const int*   batch   = (const int*)d_in[3];
  const float* embed   = (const float*)d_in[4];
  const float* Wf      = (const float*)d_in[5];
  const float* bf      = (const float*)d_in[6];
  const float* Ws      = (const float*)d_in[7];
  const float* bs      = (const float*)d_in[8];
  const float* lng     = (const float*)d_in[9];
  const float* lnb     = (const float*)d_in[10];
  const float* W1      = (const float*)d_in[11];
  const float* b1      = (const float*)d_in[12];
  const float* g1      = (const float*)d_in[13];
  const float* bt1     = (const float*)d_in[14];
  const float* W2      = (const float*)d_in[15];
  const float* b2      = (const float*)d_in[16];
  const float* g2      = (const float*)d_in[17];
  const float* bt2     = (const float*)d_in[18];
  const float* Wout    = (const float*)d_in[19];
  const float* bout    = (const float*)d_in[20];
  const int* src = eidx;
  const int* tgt = eidx + NEDGES;

  float*   x    = (float*)d_ws;                       // N*64
  float*   ptab = x    + (size_t)NNODES*64;           // N*128 fp32
  __half2* qh   = (__half2*)(ptab + (size_t)NNODES*128); // N*64 half2 (N*128 halves)
  float*   Gt   = (float*)(qh + (size_t)NNODES*64);   // 3*TBL*128
  float*   Gt2  = Gt   + (size_t)3*TBL*128;           // 3*TBL*256
  float*   Wcat = Gt2  + (size_t)3*TBL*256;           // 3*64*256
  int2*    ep   = (int2*)(Wcat + (size_t)3*64*256);   // E int2
  int*     offs = (int*)(ep + NEDGES);                // N+1
  int*     cur  = offs + NNODES + 1;                  // N
  int*     deg  = cur  + NNODES;                      // N
  int*     bsum = deg  + NNODES;                      // 128
  int*     bbase= bsum + 128;                         // 128
  float*   gsum = (float*)(bbase + 128);              // 256
  int*     gcnt = (int*)(gsum + NGRAPH);              // 256
  float*   out  = (float*)d_out;

  k_init  <<<(NNODES+255)/256, 256, 0, stream>>>(deg, gsum, gcnt);
  k_embed <<<(NNODES*64+255)/256, 256, 0, stream>>>(numbers, embed, x);

  k_hist   <<<(NEDGES+255)/256, 256, 0, stream>>>(src, deg);
  k_scan1  <<<NB1, 1024, 0, stream>>>(deg, offs, bsum);
  k_scan2  <<<1, 64, 0, stream>>>(bsum, bbase, offs);
  k_scan3  <<<(NNODES+255)/256, 256, 0, stream>>>(offs, bbase, cur);
  k_scatter<<<(NEDGES+255)/256, 256, 0, stream>>>(src, tgt, elen, cur, ep);

  k_gauss <<<3*TBL, 128, 0, stream>>>(Wf, bf, Ws, bs, Gt);
  k_gpack <<<3*TBL, 64, 0, stream>>>(Gt, Gt2);
  k_wcat  <<<(3*64*256+255)/256, 256, 0, stream>>>(Wf, Ws, Wcat);

  for (int i = 0; i < NCONV; i++){
    k_ntrans<<<NNODES/32, 256, 0, stream>>>(x, Wcat + (size_t)i*64*256, ptab, qh);
    k_edge  <<<NNODES/4, 256, 0, stream>>>(ptab, qh, offs, ep,
                                           Gt2 + (size_t)i*TBL*256,
                                           lng + i*64, lnb + i*64, x);
  }

  k_head<<<NNODES/32, 256, 0, stream>>>(x, W1, b1, g1, bt1,
                                        W2, b2, g2, bt2, Wout, batch, gsum, gcnt);
  k_final<<<1, 256, 0, stream>>>(gsum, gcnt, bout, out);
}

// Round 9
// 914.963 us; speedup vs baseline: 1.5858x; 1.0148x over previous
//
#include <hip/hip_runtime.h>
#include <hip/hip_fp16.h>
#include <math.h>

#define NNODES 100000
#define NEDGES 1600000
#define NGRAPH 256
#define NCONV  3
#define TBL    2048
#define NB1    98          // ceil(100000/1024)
#define R_MIN_ 1.0f
#define R_MAX_ 6.0f

typedef float v2f __attribute__((ext_vector_type(2)));

__device__ __forceinline__ float softplus_f(float x){
  return fmaxf(x, 0.f) + __logf(1.f + __expf(-fabsf(x)));
}
__device__ __forceinline__ float sigmoid_f(float x){
  return __builtin_amdgcn_rcpf(1.f + __expf(-x));
}
__device__ __forceinline__ void fma4(float4& a, float s, const float4 w){
  a.x = fmaf(s, w.x, a.x); a.y = fmaf(s, w.y, a.y);
  a.z = fmaf(s, w.z, a.z); a.w = fmaf(s, w.w, a.w);
}

// ---------------- init ----------------
__global__ void k_init(int* deg, float* gsum, int* gcnt){
  int i = blockIdx.x*256 + threadIdx.x;
  if (i < NNODES) deg[i] = 0;
  if (i < NGRAPH){ gsum[i] = 0.f; gcnt[i] = 0; }
}

// ---------------- embedding gather ----------------
__global__ void k_embed(const int* __restrict__ numbers, const float* __restrict__ embed,
                        float* __restrict__ x){
  int i = blockIdx.x*256 + threadIdx.x;
  if (i >= NNODES*64) return;
  int n = i >> 6, c = i & 63;
  x[i] = embed[numbers[n]*64 + c];
}

// ---------------- CSR build ----------------
__global__ void k_hist(const int* __restrict__ src, int* deg){
  int e = blockIdx.x*256 + threadIdx.x;
  if (e < NEDGES) atomicAdd(&deg[src[e]], 1);
}

__global__ void k_scan1(const int* __restrict__ deg, int* __restrict__ offs, int* __restrict__ bsum){
  __shared__ int s[1024];
  int n = blockIdx.x*1024 + threadIdx.x;
  int v = (n < NNODES) ? deg[n] : 0;
  s[threadIdx.x] = v;
  __syncthreads();
  for (int d = 1; d < 1024; d <<= 1){
    int t = (threadIdx.x >= d) ? s[threadIdx.x - d] : 0;
    __syncthreads();
    s[threadIdx.x] += t;
    __syncthreads();
  }
  int incl = s[threadIdx.x];
  if (n < NNODES) offs[n] = incl - v;
  if (threadIdx.x == 1023) bsum[blockIdx.x] = incl;
}

__global__ void k_scan2(const int* __restrict__ bsum, int* __restrict__ bbase, int* __restrict__ offs){
  if (blockIdx.x == 0 && threadIdx.x == 0){
    int run = 0;
    for (int b = 0; b < NB1; b++){ int t = bsum[b]; bbase[b] = run; run += t; }
    offs[NNODES] = NEDGES;
  }
}

__global__ void k_scan3(int* __restrict__ offs, const int* __restrict__ bbase, int* __restrict__ cur){
  int n = blockIdx.x*256 + threadIdx.x;
  if (n < NNODES){
    int o = offs[n] + bbase[n >> 10];
    offs[n] = o;
    cur[n]  = o;
  }
}

// pack edge: (tgt, idx<<16 | half(frac))
__global__ void k_scatter(const int* __restrict__ src, const int* __restrict__ tgt,
                          const float* __restrict__ elen, int* cur,
                          int2* __restrict__ ep){
  int e = blockIdx.x*256 + threadIdx.x;
  if (e >= NEDGES) return;
  int s = src[e];
  int pos = atomicAdd(&cur[s], 1);
  float key = (elen[e] - R_MIN_) * ((float)(TBL-1)/(R_MAX_-R_MIN_));
  key = fminf(fmaxf(key, 0.f), (float)(TBL-1) - 1e-3f);
  int idx = (int)key;
  float fr = key - (float)idx;
  unsigned short fh = __half_as_ushort(__float2half_rn(fr));
  ep[pos] = make_int2(tgt[e], (idx << 16) | (int)fh);
}

// ---------------- Gaussian table ----------------
__global__ void k_gauss(const float* __restrict__ Wf, const float* __restrict__ bf,
                        const float* __restrict__ Ws, const float* __restrict__ bs,
                        float* __restrict__ Gt){
  __shared__ float attr[64];
  int bi = blockIdx.x;
  int i = bi / TBL, r = bi % TBL;
  int t = threadIdx.x;
  float d = R_MIN_ + (R_MAX_-R_MIN_) * (float)r / (float)(TBL-1);
  if (t < 64){
    float cj = 1.f + 5.f * (float)t / 63.f;
    float u = (d - cj) * (64.f/5.f);
    attr[t] = __expf(-0.5f*u*u);
  }
  __syncthreads();
  int c = t >> 1;
  bool sside = (t & 1);
  const float* W = (sside ? Ws : Wf) + i*192*64 + 128*64 + c;
  float acc = (sside ? bs : bf)[i*64 + c];
  #pragma unroll 8
  for (int j = 0; j < 64; j++) acc = fmaf(attr[j], W[j*64], acc);
  Gt[(i*TBL + r)*128 + t] = acc;
}

// ---------------- pack Gt rows r, r+1 interleaved ----------------
__global__ void k_gpack(const float* __restrict__ Gt, float* __restrict__ Gt2){
  int bi = blockIdx.x;                 // 3*TBL
  int i = bi / TBL, r = bi % TBL;
  int l = threadIdx.x;                 // 0..63
  int r1 = (r + 1 < TBL) ? r + 1 : r;
  const float* g0 = Gt + ((size_t)i*TBL + r )*128;
  const float* g1 = Gt + ((size_t)i*TBL + r1)*128;
  float4 v;
  v.x = g0[2*l]; v.y = g0[2*l+1];
  v.z = g1[2*l]; v.w = g1[2*l+1];
  ((float4*)(Gt2 + ((size_t)i*TBL + r)*256))[l] = v;
}

// ---------------- Wcat pack ----------------
__global__ void k_wcat(const float* __restrict__ Wf, const float* __restrict__ Ws,
                       float* __restrict__ Wcat){
  int idx = blockIdx.x*256 + threadIdx.x;
  if (idx >= 3*64*256) return;
  int i = idx / (64*256);
  int rem = idx % (64*256);
  int k = rem / 256, c = rem % 256;
  float v;
  if (c < 128){
    int p = c >> 1; bool ss = (c & 1);
    v = (ss ? Ws : Wf)[i*192*64 + k*64 + p];
  } else {
    int p = (c-128) >> 1; bool ss = (c & 1);
    v = (ss ? Ws : Wf)[i*192*64 + (64+k)*64 + p];
  }
  Wcat[i*64*256 + k*256 + c] = v;
}

// ---------------- node transform: 32 nodes x 256 cols; p and q stored fp16 ----------------
// pqh[n][0..63]  = p (half2 per channel), pqh[n][64..127] = q
__global__ void k_ntrans(const float* __restrict__ x, const float* __restrict__ Wc,
                         __half2* __restrict__ pqh){
  __shared__ float xs[32*64];       // 8 KB
  int n0 = blockIdx.x * 32;         // 3125 blocks exact
  int t = threadIdx.x;              // 256
  ((float4*)xs)[t]       = ((const float4*)(x + (size_t)n0*64))[t];
  ((float4*)xs)[t + 256] = ((const float4*)(x + (size_t)n0*64))[t + 256];
  __syncthreads();
  int cg = t & 63, ng = t >> 6;     // 64 col-groups x 4 cols; 4 node-groups x 8 nodes
  float4 acc[8];
  #pragma unroll
  for (int i = 0; i < 8; i++) acc[i] = make_float4(0.f,0.f,0.f,0.f);
  const float* wp = Wc + 4*cg;
  const float* xp = xs + ng*8*64;
  #pragma unroll 2
  for (int k = 0; k < 64; k += 4){
    float4 w0 = *(const float4*)(wp + (k+0)*256);
    float4 w1 = *(const float4*)(wp + (k+1)*256);
    float4 w2 = *(const float4*)(wp + (k+2)*256);
    float4 w3 = *(const float4*)(wp + (k+3)*256);
    #pragma unroll
    for (int nn = 0; nn < 8; nn++){
      float4 xv = *(const float4*)(xp + nn*64 + k);
      fma4(acc[nn], xv.x, w0); fma4(acc[nn], xv.y, w1);
      fma4(acc[nn], xv.z, w2); fma4(acc[nn], xv.w, w3);
    }
  }
  // cols 4cg..4cg+3 = channels 2cg,2cg+1 of (p if cg<32 else q); dest slot is 2cg either way
  #pragma unroll
  for (int nn = 0; nn < 8; nn++){
    int node = n0 + ng*8 + nn;
    __half2 h0 = __float22half2_rn(make_float2(acc[nn].x, acc[nn].y));
    __half2 h1 = __float22half2_rn(make_float2(acc[nn].z, acc[nn].w));
    __half2* dst = pqh + (size_t)node*128 + 2*cg;
    dst[0] = h0; dst[1] = h1;
  }
}

// ---------------- edge pass: wave per node, scalar metadata, packed-f32 math ----------------
__global__ void k_edge(const __half2* __restrict__ pqh,
                       const int* __restrict__ offs, const int2* __restrict__ ep,
                       const float* __restrict__ Gt2, const float* __restrict__ lng,
                       const float* __restrict__ lnb, float* __restrict__ x){
  int wid  = (blockIdx.x*256 + threadIdx.x) >> 6;
  int lane = threadIdx.x & 63;
  int n = wid;
  float2 pp = __half22float2(pqh[(size_t)n*128 + lane]);
  v2f pv; pv.x = pp.x; pv.y = pp.y;
  int j0 = __builtin_amdgcn_readfirstlane(offs[n]);
  int j1 = __builtin_amdgcn_readfirstlane(offs[n+1]);
  float acc = 0.f;
  int u = j0;
  for (; u + 8 <= j1; u += 8){
    __half2 qr[8]; float4 gv[8]; float fr[8];
    #pragma unroll
    for (int i = 0; i < 8; i++){
      int2 e = ep[u + i];
      int tg = e.x;
      int idx = ((unsigned)e.y) >> 16;
      fr[i] = __half2float(__ushort_as_half((unsigned short)(e.y & 0xffff)));
      qr[i] = pqh[(size_t)tg*128 + 64 + lane];
      gv[i] = *(const float4*)(Gt2 + (size_t)idx*256 + 4*lane);
    }
    #pragma unroll
    for (int i = 0; i < 8; i++){
      float2 qf = __half22float2(qr[i]);
      v2f qv; qv.x = qf.x; qv.y = qf.y;
      v2f g0; g0.x = gv[i].x; g0.y = gv[i].y;
      v2f g1; g1.x = gv[i].z; g1.y = gv[i].w;
      v2f fr2; fr2.x = fr[i]; fr2.y = fr[i];
      v2f z = pv + qv + (g0 + fr2*(g1 - g0));
      acc = fmaf(sigmoid_f(z.x), softplus_f(z.y), acc);
    }
  }
  for (; u < j1; u++){
    int2 e = ep[u];
    int tg = e.x;
    int idx = ((unsigned)e.y) >> 16;
    float fr0 = __half2float(__ushort_as_half((unsigned short)(e.y & 0xffff)));
    float2 qf = __half22float2(pqh[(size_t)tg*128 + 64 + lane]);
    float4 gvv = *(const float4*)(Gt2 + (size_t)idx*256 + 4*lane);
    float rf = fmaf(fr0, gvv.z - gvv.x, gvv.x);
    float rs = fmaf(fr0, gvv.w - gvv.y, gvv.y);
    acc = fmaf(sigmoid_f(pp.x + qf.x + rf), softplus_f(pp.y + qf.y + rs), acc);
  }
  float s1 = acc, s2 = acc*acc;
  #pragma unroll
  for (int o = 32; o > 0; o >>= 1){ s1 += __shfl_xor(s1, o, 64); s2 += __shfl_xor(s2, o, 64); }
  float mu  = s1 * (1.f/64.f);
  float var = s2 * (1.f/64.f) - mu*mu;
  float inv = rsqrtf(fmaxf(var, 0.f) + 1e-5f);
  float y = (acc - mu) * inv * lng[lane] + lnb[lane];
  x[(size_t)n*64 + lane] += y;
}

// ---------------- fused head with K=8 register-prefetched weights ----------------
__global__ void k_head(const float* __restrict__ x,
                       const float* __restrict__ W1, const float* __restrict__ b1,
                       const float* __restrict__ g1, const float* __restrict__ bt1,
                       const float* __restrict__ W2, const float* __restrict__ b2,
                       const float* __restrict__ g2, const float* __restrict__ bt2,
                       const float* __restrict__ Wout, const int* __restrict__ batch,
                       float* gsum, int* gcnt){
  __shared__ float xs[32*64];       // 8 KB
  __shared__ float hs[32*128];      // 16 KB
  __shared__ float es[32];
  int n0 = blockIdx.x * 32;         // 3125 blocks
  int t = threadIdx.x;              // 256
  ((float4*)xs)[t]       = ((const float4*)(x + (size_t)n0*64))[t];
  ((float4*)xs)[t + 256] = ((const float4*)(x + (size_t)n0*64))[t + 256];
  __syncthreads();
  int cg = t & 31, ng = t >> 5;     // 32 col-groups x 4 cols; 8 node-groups x 4 nodes

  // ---- layer 1: 64 -> 128, LN, softplus, into hs ----
  {
    float4 acc[4];
    #pragma unroll
    for (int i = 0; i < 4; i++) acc[i] = make_float4(0.f,0.f,0.f,0.f);
    const float* wp = W1 + 4*cg;
    const float* xp = xs + ng*4*64;
    float4 w[8];
    #pragma unroll
    for (int j = 0; j < 8; j++) w[j] = *(const float4*)(wp + j*128);
    for (int k = 0; k < 64; k += 8){
      float4 wn[8];
      int kn = (k + 8 < 64) ? k + 8 : 0;
      #pragma unroll
      for (int j = 0; j < 8; j++) wn[j] = *(const float4*)(wp + (kn+j)*128);
      #pragma unroll
      for (int h = 0; h < 2; h++){
        #pragma unroll
        for (int nn = 0; nn < 4; nn++){
          float4 xv = *(const float4*)(xp + nn*64 + k + h*4);
          fma4(acc[nn], xv.x, w[h*4+0]); fma4(acc[nn], xv.y, w[h*4+1]);
          fma4(acc[nn], xv.z, w[h*4+2]); fma4(acc[nn], xv.w, w[h*4+3]);
        }
      }
      #pragma unroll
      for (int j = 0; j < 8; j++) w[j] = wn[j];
    }
    float4 bv  = *(const float4*)(b1  + 4*cg);
    float4 gv  = *(const float4*)(g1  + 4*cg);
    float4 btv = *(const float4*)(bt1 + 4*cg);
    #pragma unroll
    for (int nn = 0; nn < 4; nn++){
      float4 v = acc[nn];
      v.x += bv.x; v.y += bv.y; v.z += bv.z; v.w += bv.w;
      float s1 = v.x + v.y + v.z + v.w;
      float s2 = v.x*v.x + v.y*v.y + v.z*v.z + v.w*v.w;
      #pragma unroll
      for (int o = 16; o > 0; o >>= 1){ s1 += __shfl_xor(s1, o, 64); s2 += __shfl_xor(s2, o, 64); }
      float mu  = s1 * (1.f/128.f);
      float var = s2 * (1.f/128.f) - mu*mu;
      float inv = rsqrtf(fmaxf(var, 0.f) + 1e-5f);
      float4 o4;
      o4.x = softplus_f((v.x - mu)*inv*gv.x + btv.x);
      o4.y = softplus_f((v.y - mu)*inv*gv.y + btv.y);
      o4.z = softplus_f((v.z - mu)*inv*gv.z + btv.z);
      o4.w = softplus_f((v.w - mu)*inv*gv.w + btv.w);
      *(float4*)(hs + (ng*4 + nn)*128 + 4*cg) = o4;
    }
  }
  __syncthreads();

  // ---- layer 2: 128 -> 128, LN, softplus, proj -> per-node energy in es ----
  {
    float4 acc[4];
    #pragma unroll
    for (int i = 0; i < 4; i++) acc[i] = make_float4(0.f,0.f,0.f,0.f);
    const float* wp = W2 + 4*cg;
    const float* hp = hs + ng*4*128;
    float4 w[8];
    #pragma unroll
    for (int j = 0; j < 8; j++) w[j] = *(const float4*)(wp + j*128);
    for (int k = 0; k < 128; k += 8){
      float4 wn[8];
      int kn = (k + 8 < 128) ? k + 8 : 0;
      #pragma unroll
      for (int j = 0; j < 8; j++) wn[j] = *(const float4*)(wp + (kn+j)*128);
      #pragma unroll
      for (int h = 0; h < 2; h++){
        #pragma unroll
        for (int nn = 0; nn < 4; nn++){
          float4 hv = *(const float4*)(hp + nn*128 + k + h*4);
          fma4(acc[nn], hv.x, w[h*4+0]); fma4(acc[nn], hv.y, w[h*4+1]);
          fma4(acc[nn], hv.z, w[h*4+2]); fma4(acc[nn], hv.w, w[h*4+3]);
        }
      }
      #pragma unroll
      for (int j = 0; j < 8; j++) w[j] = wn[j];
    }
    float4 bv  = *(const float4*)(b2  + 4*cg);
    float4 gv  = *(const float4*)(g2  + 4*cg);
    float4 btv = *(const float4*)(bt2 + 4*cg);
    float4 wo  = *(const float4*)(Wout + 4*cg);
    #pragma unroll
    for (int nn = 0; nn < 4; nn++){
      float4 v = acc[nn];
      v.x += bv.x; v.y += bv.y; v.z += bv.z; v.w += bv.w;
      float s1 = v.x + v.y + v.z + v.w;
      float s2 = v.x*v.x + v.y*v.y + v.z*v.z + v.w*v.w;
      #pragma unroll
      for (int o = 16; o > 0; o >>= 1){ s1 += __shfl_xor(s1, o, 64); s2 += __shfl_xor(s2, o, 64); }
      float mu  = s1 * (1.f/128.f);
      float var = s2 * (1.f/128.f) - mu*mu;
      float inv = rsqrtf(fmaxf(var, 0.f) + 1e-5f);
      float ev = softplus_f((v.x - mu)*inv*gv.x + btv.x) * wo.x
               + softplus_f((v.y - mu)*inv*gv.y + btv.y) * wo.y
               + softplus_f((v.z - mu)*inv*gv.z + btv.z) * wo.z
               + softplus_f((v.w - mu)*inv*gv.w + btv.w) * wo.w;
      #pragma unroll
      for (int o = 16; o > 0; o >>= 1) ev += __shfl_xor(ev, o, 64);
      if (cg == 0) es[ng*4 + nn] = ev;
    }
  }
  __syncthreads();

  // ---- segmented reduction over the sorted 32-node tile ----
  if (t < 32){
    int node = n0 + t;
    int g = batch[node];
    bool head = (t == 0) || (batch[node-1] != g);
    if (head){
      float s = 0.f; int c = 0;
      int j = t;
      while (j < 32 && batch[n0+j] == g){ s += es[j]; c++; j++; }
      atomicAdd(&gsum[g], s);
      atomicAdd(&gcnt[g], c);
    }
  }
}

// ---------------- final ----------------
__global__ void k_final(const float* __restrict__ gsum, const int* __restrict__ gcnt,
                        const float* __restrict__ bout, float* __restrict__ out){
  int g = threadIdx.x;
  if (g < NGRAPH)
    out[g] = gsum[g] / fmaxf((float)gcnt[g], 1.f) + bout[0];
}

extern "C" void kernel_launch(void* const* d_in, const int* in_sizes, int n_in,
                              void* d_out, int out_size, void* d_ws, size_t ws_size,
                              hipStream_t stream){
  const int*   numbers = (const int*)d_in[0];
  const int*   eidx    = (const int*)d_in[1];
  const float* elen    = (const float*)d_in[2];
  const int*   batch   = (const int*)d_in[3];
  const float* embed   = (const float*)d_in[4];
  const float* Wf      = (const float*)d_in[5];
  const float* bf      = (const float*)d_in[6];
  const float* Ws      = (const float*)d_in[7];
  const float* bs      = (const float*)d_in[8];
  const float* lng     = (const float*)d_in[9];
  const float* lnb     = (const float*)d_in[10];
  const float* W1      = (const float*)d_in[11];
  const float* b1      = (const float*)d_in[12];
  const float* g1      = (const float*)d_in[13];
  const float* bt1     = (const float*)d_in[14];
  const float* W2      = (const float*)d_in[15];
  const float* b2      = (const float*)d_in[16];
  const float* g2      = (const float*)d_in[17];
  const float* bt2     = (const float*)d_in[18];
  const float* Wout    = (const float*)d_in[19];
  const float* bout    = (const float*)d_in[20];
  const int* src = eidx;
  const int* tgt = eidx + NEDGES;

  float*   x    = (float*)d_ws;                          // N*64 f32
  __half2* pqh  = (__half2*)(x + (size_t)NNODES*64);     // N*128 half2
  float*   Gt   = (float*)(pqh + (size_t)NNODES*128);    // 3*TBL*128 f32
  float*   Gt2  = Gt   + (size_t)3*TBL*128;              // 3*TBL*256 f32
  float*   Wcat = Gt2  + (size_t)3*TBL*256;              // 3*64*256
  int2*    ep   = (int2*)(Wcat + (size_t)3*64*256);      // E int2
  int*     offs = (int*)(ep + NEDGES);                   // N+1
  int*     cur  = offs + NNODES + 1;                     // N
  int*     deg  = cur  + NNODES;                         // N
  int*     bsum = deg  + NNODES;                         // 128
  int*     bbase= bsum + 128;                            // 128
  float*   gsum = (float*)(bbase + 128);                 // 256
  int*     gcnt = (int*)(gsum + NGRAPH);                 // 256
  float*   out  = (float*)d_out;

  k_init  <<<(NNODES+255)/256, 256, 0, stream>>>(deg, gsum, gcnt);
  k_embed <<<(NNODES*64+255)/256, 256, 0, stream>>>(numbers, embed, x);

  k_hist   <<<(NEDGES+255)/256, 256, 0, stream>>>(src, deg);
  k_scan1  <<<NB1, 1024, 0, stream>>>(deg, offs, bsum);
  k_scan2  <<<1, 64, 0, stream>>>(bsum, bbase, offs);
  k_scan3  <<<(NNODES+255)/256, 256, 0, stream>>>(offs, bbase, cur);
  k_scatter<<<(NEDGES+255)/256, 256, 0, stream>>>(src, tgt, elen, cur, ep);

  k_gauss <<<3*TBL, 128, 0, stream>>>(Wf, bf, Ws, bs, Gt);
  k_gpack <<<3*TBL, 64, 0, stream>>>(Gt, Gt2);
  k_wcat  <<<(3*64*256+255)/256, 256, 0, stream>>>(Wf, Ws, Wcat);

  for (int i = 0; i < NCONV; i++){
    k_ntrans<<<NNODES/32, 256, 0, stream>>>(x, Wcat + (size_t)i*64*256, pqh);
    k_edge  <<<NNODES/4, 256, 0, stream>>>(pqh, offs, ep,
                                           Gt2 + (size_t)i*TBL*256,
                                           lng + i*64, lnb + i*64, x);
  }

  k_head<<<NNODES/32, 256, 0, stream>>>(x, W1, b1, g1, bt1,
                                        W2, b2, g2, bt2, Wout, batch, gsum, gcnt);
  k_final<<<1, 256, 0, stream>>>(gsum, gcnt, bout, out);
}